// Round 3
// baseline (514.275 us; speedup 1.0000x reference)
//
#include <hip/hip_runtime.h>
#include <hip/hip_bf16.h>
#include <math.h>

#define B_      16
#define L_      2048
#define D_MODEL 320
#define D_INNER 640
#define D_STATE 16
#define DT_RANK 20
#define H_OUT   128
#define VOCAB   65
#define N_TIS   30
#define XDBL    52   // DT_RANK + 2*D_STATE
#define TT      16   // t-tile in producer

// workspace layout (floats)
static constexpr size_t OFF_MSEQ  = 0;                         // 65*1280
static constexpr size_t OFF_MTIS  = OFF_MSEQ + VOCAB*1280;     // 30*1280
static constexpr size_t OFF_YSCAN = OFF_MTIS + N_TIS*1280;     // 16*640
static constexpr size_t OFF_DELTA = OFF_YSCAN + B_*D_INNER;    // 16*640*2048
static constexpr size_t OFF_DU    = OFF_DELTA + (size_t)B_*D_INNER*L_;
static constexpr size_t OFF_BBAR  = OFF_DU    + (size_t)B_*D_INNER*L_;
static constexpr size_t OFF_CLAST = OFF_BBAR  + (size_t)B_*D_STATE*L_;   // 16*16

__device__ __forceinline__ float silu_f(float x) { return x / (1.0f + __expf(-x)); }

// ---------- A0+A1 fused: renorm embedding row (max_norm=2) then M-row = row @ inW-slice^T ----------
__global__ __launch_bounds__(256) void k_mbuild(
    const float* __restrict__ seqW, const float* __restrict__ tisW,
    const float* __restrict__ inW, float* __restrict__ ws)
{
    __shared__ float a_l[256];
    __shared__ float red[4];
    int v = blockIdx.x, tid = threadIdx.x;
    int K, wofs; const float* src; float* dstM;
    if (v < VOCAB) { K = 256; wofs = 0;   src = seqW + (size_t)v*256;        dstM = ws + OFF_MSEQ + (size_t)v*1280; }
    else           { K = 64;  wofs = 256; src = tisW + (size_t)(v-VOCAB)*64; dstM = ws + OFF_MTIS + (size_t)(v-VOCAB)*1280; }
    float x = (tid < K) ? src[tid] : 0.0f;
    float ss = x * x;
    #pragma unroll
    for (int o = 32; o; o >>= 1) ss += __shfl_xor(ss, o);
    if ((tid & 63) == 0) red[tid >> 6] = ss;
    __syncthreads();
    float tot = red[0] + red[1] + red[2] + red[3];
    float scale = fminf(1.0f, 2.0f / fmaxf(sqrtf(tot), 1e-12f));
    if (tid < K) a_l[tid] = x * scale;
    __syncthreads();

    int j = blockIdx.y * 256 + tid;   // 5*256=1280 columns
    const float* w = inW + (size_t)j*320 + wofs;
    float ac0 = 0.f, ac1 = 0.f, ac2 = 0.f, ac3 = 0.f;
    #pragma unroll 4
    for (int k = 0; k < K; k += 4) {
        float4 w4 = *(const float4*)(w + k);
        ac0 += a_l[k+0]*w4.x; ac1 += a_l[k+1]*w4.y;
        ac2 += a_l[k+2]*w4.z; ac3 += a_l[k+3]*w4.w;
    }
    dstM[j] = (ac0 + ac1) + (ac2 + ac3);
}

// ---------- K2: conv+silu -> x_proj (reg-cached W, butterfly reduce) -> dt_proj+softplus ----------
// writes delta, delta*u in [b,d,t]; Bbar [b,s,t]; C only at t_last -> Clast[b][16]
__global__ __launch_bounds__(256, 3) void k_produce(
    const int* __restrict__ idx, const int* __restrict__ tissue_id,
    const int* __restrict__ seq_lengths,
    const float* __restrict__ conv_w, const float* __restrict__ conv_b,
    const float* __restrict__ xW, const float* __restrict__ dtW,
    const float* __restrict__ dtb, float* __restrict__ ws)
{
    __shared__ float u_l[TT*641];     // [t][d], stride 641
    __shared__ float xd_l[TT*53];     // rows 0..19 dt, 20..35 B
    __shared__ int   idx_l[TT+3];
    int b = blockIdx.y;
    int t0 = blockIdx.x * TT;
    int t_last = seq_lengths[b] - 1;
    if (t0 > t_last) return;
    int tid = threadIdx.x;
    const float* Mseq = ws + OFF_MSEQ;
    const float* Mtis = ws + OFF_MTIS;
    int tis = tissue_id[b];
    if (tid < TT+3) {
        int t = t0 - 3 + tid;
        idx_l[tid] = (t >= 0) ? idx[b*L_ + t] : 0;
    }
    __syncthreads();

    // phase 1: u = silu(causal depthwise conv4 of xz[:, :640])
    for (int d = tid; d < D_INNER; d += 256) {
        float w0 = conv_w[d*4+0], w1 = conv_w[d*4+1], w2 = conv_w[d*4+2], w3 = conv_w[d*4+3];
        float cb = conv_b[d];
        float mt = Mtis[(size_t)tis*1280 + d];
        auto XZ = [&](int k) -> float {
            int row = idx_l[k];
            return row ? (Mseq[(size_t)row*1280 + d] + mt) : 0.0f;
        };
        float a0 = XZ(0), a1 = XZ(1), a2 = XZ(2);
        for (int t = 0; t < TT; ++t) {
            float a3 = XZ(t+3);
            float c = w0*a0 + w1*a1 + w2*a2 + w3*a3 + cb;
            u_l[t*641 + d] = silu_f(c);
            a0 = a1; a1 = a2; a2 = a3;
        }
    }
    __syncthreads();

    // phase 2: x_dbl rows 0..35 for all t. Wave w handles r = w+4k (k<9).
    // Lane l owns d = {l + 64i, i<10}; W cached in 90 regs, reused across 16 t.
    {
        int w = tid >> 6, l = tid & 63;
        float wreg[9][10];
        #pragma unroll
        for (int k = 0; k < 9; ++k) {
            const float* xr = xW + (size_t)(w + 4*k)*D_INNER + l;
            #pragma unroll
            for (int i = 0; i < 10; ++i) wreg[k][i] = xr[64*i];
        }
        for (int t = 0; t < TT; ++t) {
            float ur[10];
            #pragma unroll
            for (int i = 0; i < 10; ++i) ur[i] = u_l[t*641 + l + 64*i];
            #pragma unroll
            for (int k = 0; k < 9; ++k) {
                float p = 0.f;
                #pragma unroll
                for (int i = 0; i < 10; ++i) p = fmaf(wreg[k][i], ur[i], p);
                #pragma unroll
                for (int o = 32; o; o >>= 1) p += __shfl_xor(p, o);
                if (l == t) xd_l[t*53 + w + 4*k] = p;
            }
        }
        // C rows (36..51): only the timestep t_last is ever consumed
        if (t_last < t0 + TT) {
            int tl = t_last - t0;
            float ur[10];
            #pragma unroll
            for (int i = 0; i < 10; ++i) ur[i] = u_l[tl*641 + l + 64*i];
            #pragma unroll
            for (int k = 0; k < 4; ++k) {
                const float* xr = xW + (size_t)(36 + w + 4*k)*D_INNER + l;
                float p = 0.f;
                #pragma unroll
                for (int i = 0; i < 10; ++i) p = fmaf(xr[64*i], ur[i], p);
                #pragma unroll
                for (int o = 32; o; o >>= 1) p += __shfl_xor(p, o);
                if (l == 0) ws[OFF_CLAST + b*16 + w + 4*k] = p;
            }
        }
    }
    __syncthreads();

    // phase 3: delta = softplus(dt @ dtW^T + b); write delta & delta*u as float4 runs of t
    float* delta_g = ws + OFF_DELTA + (size_t)b*D_INNER*L_;
    float* du_g    = ws + OFF_DU    + (size_t)b*D_INNER*L_;
    for (int d = tid; d < D_INNER; d += 256) {
        float wr[20];
        #pragma unroll
        for (int i = 0; i < 20; i += 4) {
            float4 w4 = *(const float4*)(dtW + d*20 + i);
            wr[i] = w4.x; wr[i+1] = w4.y; wr[i+2] = w4.z; wr[i+3] = w4.w;
        }
        float bd = dtb[d];
        float dl16[16], du16[16];
        #pragma unroll
        for (int t = 0; t < TT; ++t) {
            float x = bd;
            #pragma unroll
            for (int r = 0; r < 20; ++r) x = fmaf(xd_l[t*53 + r], wr[r], x);
            float sp = fmaxf(x, 0.0f) + log1pf(__expf(-fabsf(x)));   // stable softplus
            dl16[t] = sp;
            du16[t] = sp * u_l[t*641 + d];
        }
        float* dp = delta_g + (size_t)d*L_ + t0;
        float* up = du_g    + (size_t)d*L_ + t0;
        #pragma unroll
        for (int j = 0; j < 4; ++j) {
            *(float4*)(dp + 4*j) = make_float4(dl16[4*j], dl16[4*j+1], dl16[4*j+2], dl16[4*j+3]);
            *(float4*)(up + 4*j) = make_float4(du16[4*j], du16[4*j+1], du16[4*j+2], du16[4*j+3]);
        }
    }
    {
        int s = tid >> 4, t = tid & 15;
        ws[OFF_BBAR + ((size_t)b*D_STATE + s)*L_ + t0 + t] = xd_l[t*53 + DT_RANK + s];
    }
}

// ---------- K4: selective scan; thread = (d,s) channel; emit y at t_last only ----------
__global__ __launch_bounds__(256) void k_scan(const int* __restrict__ seq_lengths,
                                              const float* __restrict__ A_log,
                                              float* __restrict__ ws)
{
    __shared__ float dl_l[16*68], du_l[16*68], Bb_l[16*68];
    int b = blockIdx.y, dg = blockIdx.x;
    int tid = threadIdx.x;
    int dl = tid >> 4, s = tid & 15;
    int d = dg*16 + dl;
    float A = -__expf(A_log[d*D_STATE + s]);
    int t_last = seq_lengths[b] - 1;
    int lr = tid >> 4, lc = (tid & 15) * 4;
    const float* dR = ws + OFF_DELTA + ((size_t)b*D_INNER + dg*16 + lr)*L_;
    const float* uR = ws + OFF_DU    + ((size_t)b*D_INNER + dg*16 + lr)*L_;
    const float* bR = ws + OFF_BBAR  + ((size_t)b*D_STATE + lr)*L_;
    float h = 0.0f;
    for (int t0 = 0; t0 <= t_last; t0 += 64) {
        *(float4*)(dl_l + lr*68 + lc) = *(const float4*)(dR + t0 + lc);
        *(float4*)(du_l + lr*68 + lc) = *(const float4*)(uR + t0 + lc);
        *(float4*)(Bb_l + lr*68 + lc) = *(const float4*)(bR + t0 + lc);
        __syncthreads();
        if (t0 + 63 <= t_last) {
            #pragma unroll 4
            for (int q = 0; q < 16; ++q) {
                float4 d4 = *(const float4*)(dl_l + dl*68 + 4*q);
                float4 u4 = *(const float4*)(du_l + dl*68 + 4*q);
                float4 b4 = *(const float4*)(Bb_l + s*68 + 4*q);
                h = fmaf(__expf(d4.x*A), h, u4.x*b4.x);
                h = fmaf(__expf(d4.y*A), h, u4.y*b4.y);
                h = fmaf(__expf(d4.z*A), h, u4.z*b4.z);
                h = fmaf(__expf(d4.w*A), h, u4.w*b4.w);
            }
        } else {
            int tend = t_last - t0;
            for (int tt = 0; tt <= tend; ++tt) {
                float dlt = dl_l[dl*68 + tt];
                float dA  = __expf(dlt * A);
                float dbu = du_l[dl*68 + tt] * Bb_l[s*68 + tt];
                h = fmaf(dA, h, dbu);
            }
        }
        __syncthreads();
    }
    float c = ws[OFF_CLAST + b*16 + s];
    float v = h * c;
    v += __shfl_xor(v, 1); v += __shfl_xor(v, 2);
    v += __shfl_xor(v, 4); v += __shfl_xor(v, 8);
    if (s == 0) ws[OFF_YSCAN + (size_t)b*D_INNER + d] = v;
}

// ---------- K5: per-batch epilogue: skip + gate + out_proj + MLP head ----------
__global__ __launch_bounds__(320) void k_final(
    const int* __restrict__ idx, const int* __restrict__ tissue_id,
    const int* __restrict__ seq_lengths,
    const float* __restrict__ conv_w, const float* __restrict__ conv_b,
    const float* __restrict__ Dskip, const float* __restrict__ outW,
    const float* __restrict__ p1W, const float* __restrict__ p1b,
    const float* __restrict__ p2W, const float* __restrict__ p2b,
    const float* __restrict__ ws, float* __restrict__ out)
{
    __shared__ float y_l[D_INNER];
    __shared__ float o_l[D_MODEL];
    __shared__ float h1_l[H_OUT];
    int b = blockIdx.x, tid = threadIdx.x;
    int t_last = seq_lengths[b] - 1;
    int tis = tissue_id[b];
    const float* Mseq = ws + OFF_MSEQ;
    const float* Mtis = ws + OFF_MTIS;
    int rows[4];
    #pragma unroll
    for (int k = 0; k < 4; ++k) {
        int t = t_last - 3 + k;
        rows[k] = (t >= 0) ? idx[b*L_ + t] : 0;
    }
    for (int d = tid; d < D_INNER; d += 320) {
        float conv = conv_b[d];
        const float* cw = conv_w + d*4;
        #pragma unroll
        for (int k = 0; k < 4; ++k) {
            int row = rows[k];
            float xz = row ? (Mseq[(size_t)row*1280 + d] + Mtis[(size_t)tis*1280 + d]) : 0.0f;
            conv += cw[k] * xz;
        }
        float u = silu_f(conv);
        int rowL = rows[3];
        float z = rowL ? (Mseq[(size_t)rowL*1280 + 640 + d] + Mtis[(size_t)tis*1280 + 640 + d]) : 0.0f;
        float ys = ws[OFF_YSCAN + (size_t)b*D_INNER + d];
        y_l[d] = (ys + u * Dskip[d]) * silu_f(z);
    }
    __syncthreads();
    if (tid < D_MODEL) {
        const float* w = outW + tid*D_INNER;
        float acc = 0.f;
        #pragma unroll 4
        for (int k = 0; k < D_INNER; k += 4) {
            float4 w4 = *(const float4*)(w + k);
            acc += y_l[k]*w4.x + y_l[k+1]*w4.y + y_l[k+2]*w4.z + y_l[k+3]*w4.w;
        }
        o_l[tid] = acc;
    }
    __syncthreads();
    if (tid < H_OUT) {
        const float* w = p1W + tid*D_MODEL;
        float acc = p1b[tid];
        #pragma unroll 4
        for (int k = 0; k < D_MODEL; k += 4) {
            float4 w4 = *(const float4*)(w + k);
            acc += o_l[k]*w4.x + o_l[k+1]*w4.y + o_l[k+2]*w4.z + o_l[k+3]*w4.w;
        }
        h1_l[tid] = fmaxf(acc, 0.0f);
    }
    __syncthreads();
    if (tid == 0) {
        float acc = p2b[0];
        for (int k = 0; k < H_OUT; ++k) acc += h1_l[k]*p2W[k];
        out[b] = acc;
    }
}

extern "C" void kernel_launch(void* const* d_in, const int* in_sizes, int n_in,
                              void* d_out, int out_size, void* d_ws, size_t ws_size,
                              hipStream_t stream)
{
    const int*   idx   = (const int*)d_in[0];
    const int*   tis   = (const int*)d_in[1];
    const int*   slen  = (const int*)d_in[2];
    const float* seqW  = (const float*)d_in[3];
    const float* tisW  = (const float*)d_in[4];
    const float* inW   = (const float*)d_in[5];
    const float* convw = (const float*)d_in[6];
    const float* convb = (const float*)d_in[7];
    const float* xW    = (const float*)d_in[8];
    const float* dtW   = (const float*)d_in[9];
    const float* dtb   = (const float*)d_in[10];
    const float* Alog  = (const float*)d_in[11];
    const float* Dsk   = (const float*)d_in[12];
    const float* outW  = (const float*)d_in[13];
    const float* p1W   = (const float*)d_in[14];
    const float* p1b   = (const float*)d_in[15];
    const float* p2W   = (const float*)d_in[16];
    const float* p2b   = (const float*)d_in[17];
    float* ws  = (float*)d_ws;
    float* out = (float*)d_out;

    hipLaunchKernelGGL(k_mbuild,  dim3(VOCAB + N_TIS, 5), dim3(256), 0, stream, seqW, tisW, inW, ws);
    hipLaunchKernelGGL(k_produce, dim3(L_/TT, B_),        dim3(256), 0, stream,
                       idx, tis, slen, convw, convb, xW, dtW, dtb, ws);
    hipLaunchKernelGGL(k_scan,    dim3(D_INNER/16, B_),   dim3(256), 0, stream, slen, Alog, ws);
    hipLaunchKernelGGL(k_final,   dim3(B_),               dim3(320), 0, stream,
                       idx, tis, slen, convw, convb, Dsk, outW, p1W, p1b, p2W, p2b, ws, out);
}

// Round 4
// 389.934 us; speedup vs baseline: 1.3189x; 1.3189x over previous
//
#include <hip/hip_runtime.h>
#include <hip/hip_bf16.h>
#include <math.h>

#define B_      16
#define L_      2048
#define D_MODEL 320
#define D_INNER 640
#define D_STATE 16
#define DT_RANK 20
#define H_OUT   128
#define VOCAB   65
#define N_TIS   30
#define TT      16   // t-tile in xdbl producer
#define ST      64   // t-tile in fused scan

// workspace layout (floats)
static constexpr size_t OFF_MSEQ  = 0;                          // 65*1280
static constexpr size_t OFF_MTIS  = OFF_MSEQ + VOCAB*1280;      // 30*1280
static constexpr size_t OFF_YSCAN = OFF_MTIS + N_TIS*1280;      // 16*640
static constexpr size_t OFF_CLAST = OFF_YSCAN + B_*D_INNER;     // 16*16
static constexpr size_t OFF_XD    = OFF_CLAST + B_*16;          // B*L*36 (rows 0..19 dt, 20..35 B)

__device__ __forceinline__ float silu_f(float x) { return x / (1.0f + __expf(-x)); }

// ---------- A0+A1 fused: renorm embedding row (max_norm=2) then M-row = row @ inW-slice^T ----------
__global__ __launch_bounds__(256) void k_mbuild(
    const float* __restrict__ seqW, const float* __restrict__ tisW,
    const float* __restrict__ inW, float* __restrict__ ws)
{
    __shared__ float a_l[256];
    __shared__ float red[4];
    int v = blockIdx.x, tid = threadIdx.x;
    int K, wofs; const float* src; float* dstM;
    if (v < VOCAB) { K = 256; wofs = 0;   src = seqW + (size_t)v*256;        dstM = ws + OFF_MSEQ + (size_t)v*1280; }
    else           { K = 64;  wofs = 256; src = tisW + (size_t)(v-VOCAB)*64; dstM = ws + OFF_MTIS + (size_t)(v-VOCAB)*1280; }
    float x = (tid < K) ? src[tid] : 0.0f;
    float ss = x * x;
    #pragma unroll
    for (int o = 32; o; o >>= 1) ss += __shfl_xor(ss, o);
    if ((tid & 63) == 0) red[tid >> 6] = ss;
    __syncthreads();
    float tot = red[0] + red[1] + red[2] + red[3];
    float scale = fminf(1.0f, 2.0f / fmaxf(sqrtf(tot), 1e-12f));
    if (tid < K) a_l[tid] = x * scale;
    __syncthreads();

    int j = blockIdx.y * 256 + tid;   // 5*256=1280 columns
    const float* w = inW + (size_t)j*320 + wofs;
    float ac0 = 0.f, ac1 = 0.f, ac2 = 0.f, ac3 = 0.f;
    #pragma unroll 4
    for (int k = 0; k < K; k += 4) {
        float4 w4 = *(const float4*)(w + k);
        ac0 += a_l[k+0]*w4.x; ac1 += a_l[k+1]*w4.y;
        ac2 += a_l[k+2]*w4.z; ac3 += a_l[k+3]*w4.w;
    }
    dstM[j] = (ac0 + ac1) + (ac2 + ac3);
}

// ---------- K2: conv+silu -> x_proj rows 0..35 -> xd[b][t][36]; C rows only at t_last ----------
__global__ __launch_bounds__(256) void k_xdbl(
    const int* __restrict__ idx, const int* __restrict__ tissue_id,
    const int* __restrict__ seq_lengths,
    const float* __restrict__ conv_w, const float* __restrict__ conv_b,
    const float* __restrict__ xW, float* __restrict__ ws)
{
    __shared__ float u_l[TT*641];     // [t][d], stride 641
    __shared__ float xd_l[TT*36];
    __shared__ int   idx_l[TT+3];
    int b = blockIdx.y;
    int t0 = blockIdx.x * TT;
    int t_last = seq_lengths[b] - 1;
    if (t0 > t_last) return;
    int tid = threadIdx.x;
    const float* Mseq = ws + OFF_MSEQ;
    const float* Mtis = ws + OFF_MTIS;
    int tis = tissue_id[b];
    if (tid < TT+3) {
        int t = t0 - 3 + tid;
        idx_l[tid] = (t >= 0) ? idx[b*L_ + t] : 0;
    }
    __syncthreads();

    // phase 1: u = silu(causal depthwise conv4 of xz[:, :640])
    for (int d = tid; d < D_INNER; d += 256) {
        float w0 = conv_w[d*4+0], w1 = conv_w[d*4+1], w2 = conv_w[d*4+2], w3 = conv_w[d*4+3];
        float cb = conv_b[d];
        float mt = Mtis[(size_t)tis*1280 + d];
        auto XZ = [&](int k) -> float {
            int row = idx_l[k];
            return row ? (Mseq[(size_t)row*1280 + d] + mt) : 0.0f;
        };
        float a0 = XZ(0), a1 = XZ(1), a2 = XZ(2);
        for (int t = 0; t < TT; ++t) {
            float a3 = XZ(t+3);
            float c = w0*a0 + w1*a1 + w2*a2 + w3*a3 + cb;
            u_l[t*641 + d] = silu_f(c);
            a0 = a1; a1 = a2; a2 = a3;
        }
    }
    __syncthreads();

    // phase 2: rows 0..35 via 3 passes of 3 rows/wave (wreg[3][10] -> no spill)
    {
        int w = tid >> 6, l = tid & 63;
        #pragma unroll 1
        for (int pass = 0; pass < 3; ++pass) {
            float wreg[3][10];
            #pragma unroll
            for (int kk = 0; kk < 3; ++kk) {
                const float* xr = xW + (size_t)(w + 4*(3*pass + kk))*D_INNER + l;
                #pragma unroll
                for (int i = 0; i < 10; ++i) wreg[kk][i] = xr[64*i];
            }
            for (int t = 0; t < TT; ++t) {
                float ur[10];
                #pragma unroll
                for (int i = 0; i < 10; ++i) ur[i] = u_l[t*641 + l + 64*i];
                #pragma unroll
                for (int kk = 0; kk < 3; ++kk) {
                    float p = 0.f;
                    #pragma unroll
                    for (int i = 0; i < 10; ++i) p = fmaf(wreg[kk][i], ur[i], p);
                    #pragma unroll
                    for (int o = 32; o; o >>= 1) p += __shfl_xor(p, o);
                    if (l == t) xd_l[t*36 + w + 4*(3*pass + kk)] = p;
                }
            }
        }
        // C rows (xW rows 36..51): only t_last is consumed
        if (t_last < t0 + TT) {
            int tl = t_last - t0;
            float ur[10];
            #pragma unroll
            for (int i = 0; i < 10; ++i) ur[i] = u_l[tl*641 + l + 64*i];
            #pragma unroll
            for (int k = 0; k < 4; ++k) {
                const float* xr = xW + (size_t)(36 + w + 4*k)*D_INNER + l;
                float p = 0.f;
                #pragma unroll
                for (int i = 0; i < 10; ++i) p = fmaf(xr[64*i], ur[i], p);
                #pragma unroll
                for (int o = 32; o; o >>= 1) p += __shfl_xor(p, o);
                if (l == 0) ws[OFF_CLAST + b*16 + w + 4*k] = p;
            }
        }
    }
    __syncthreads();

    // write xd tile (coalesced)
    {
        int tmax = min(TT-1, t_last - t0);
        int cnt = (tmax + 1) * 36;
        float* dst = ws + OFF_XD + ((size_t)b*L_ + t0)*36;
        for (int o = tid; o < cnt; o += 256) dst[o] = xd_l[o];
    }
}

// ---------- K3: fused dt_proj/softplus/conv-u + selective scan; y at t_last only ----------
// grid (40, B), block 256. Recurrence threads: (dl = tid>>4, s = tid&15).
__global__ __launch_bounds__(256) void k_scanf(
    const int* __restrict__ idx, const int* __restrict__ tissue_id,
    const int* __restrict__ seq_lengths,
    const float* __restrict__ conv_w, const float* __restrict__ conv_b,
    const float* __restrict__ dtW, const float* __restrict__ dtb,
    const float* __restrict__ A_log, float* __restrict__ ws)
{
    __shared__ float xd_t[ST*36];          // [t][36]
    __shared__ float dl_t[16*68];          // [d][t]
    __shared__ float du_t[16*68];
    __shared__ float dtw_l[16*20];
    __shared__ float cw_l[16*4];
    __shared__ float cb_l[16], dtb_l[16], mt_l[16];
    __shared__ int   idx_t[ST+3];

    int b = blockIdx.y, dg = blockIdx.x;
    int tid = threadIdx.x;
    int dl = tid >> 4, s = tid & 15;
    int t_last = seq_lengths[b] - 1;
    int tis = tissue_id[b];
    const float* Mseq = ws + OFF_MSEQ;

    if (tid < 16) {
        int d = dg*16 + tid;
        cb_l[tid]  = conv_b[d];
        dtb_l[tid] = dtb[d];
        mt_l[tid]  = ws[OFF_MTIS + (size_t)tis*1280 + d];
    }
    if (tid < 64) {
        int dd = tid >> 2, k = tid & 3;
        cw_l[dd*4 + k] = conv_w[(dg*16 + dd)*4 + k];
    }
    for (int o = tid; o < 16*20; o += 256) {
        int dd = o / 20, r = o % 20;
        dtw_l[o] = dtW[(dg*16 + dd)*20 + r];
    }
    float A = -__expf(A_log[(dg*16 + dl)*D_STATE + s]);

    float h = 0.0f;
    for (int t0 = 0; t0 <= t_last; t0 += ST) {
        int nt = min(ST, t_last - t0 + 1);
        if (tid < ST+3) {
            int t = t0 - 3 + tid;
            idx_t[tid] = (t >= 0 && t < L_) ? idx[b*L_ + t] : 0;
        }
        {
            const float* src = ws + OFF_XD + ((size_t)b*L_ + t0)*36;
            int cnt = nt * 36;
            for (int o = tid; o < cnt; o += 256) xd_t[o] = src[o];
        }
        __syncthreads();

        // produce delta / du for 16 d x nt t: thread = (tt = tid>>2, 4 consecutive d)
        {
            int tt = tid >> 2, dd0 = (tid & 3) * 4;
            if (tt < nt) {
                float cc0 = cb_l[dd0+0], cc1 = cb_l[dd0+1], cc2 = cb_l[dd0+2], cc3 = cb_l[dd0+3];
                #pragma unroll
                for (int k = 0; k < 4; ++k) {
                    int row = idx_t[tt + k];
                    float4 m;
                    if (row) {
                        m = *(const float4*)(Mseq + (size_t)row*1280 + dg*16 + dd0);
                        m.x += mt_l[dd0+0]; m.y += mt_l[dd0+1];
                        m.z += mt_l[dd0+2]; m.w += mt_l[dd0+3];
                    } else m = make_float4(0.f,0.f,0.f,0.f);
                    cc0 = fmaf(cw_l[(dd0+0)*4+k], m.x, cc0);
                    cc1 = fmaf(cw_l[(dd0+1)*4+k], m.y, cc1);
                    cc2 = fmaf(cw_l[(dd0+2)*4+k], m.z, cc2);
                    cc3 = fmaf(cw_l[(dd0+3)*4+k], m.w, cc3);
                }
                float uu[4] = { silu_f(cc0), silu_f(cc1), silu_f(cc2), silu_f(cc3) };
                float xdr[20];
                #pragma unroll
                for (int r = 0; r < 20; ++r) xdr[r] = xd_t[tt*36 + r];
                #pragma unroll
                for (int i = 0; i < 4; ++i) {
                    int d = dd0 + i;
                    float x = dtb_l[d];
                    #pragma unroll
                    for (int r = 0; r < 20; ++r) x = fmaf(xdr[r], dtw_l[d*20 + r], x);
                    float sp = fmaxf(x, 0.0f) + log1pf(__expf(-fabsf(x)));
                    dl_t[d*68 + tt] = sp;
                    du_t[d*68 + tt] = sp * uu[i];
                }
            }
        }
        __syncthreads();

        // recurrence
        {
            int q4 = nt >> 2;
            for (int q = 0; q < q4; ++q) {
                float4 d4 = *(const float4*)(dl_t + dl*68 + 4*q);
                float4 u4 = *(const float4*)(du_t + dl*68 + 4*q);
                float b0 = xd_t[(4*q+0)*36 + 20 + s];
                float b1 = xd_t[(4*q+1)*36 + 20 + s];
                float b2 = xd_t[(4*q+2)*36 + 20 + s];
                float b3 = xd_t[(4*q+3)*36 + 20 + s];
                h = fmaf(__expf(d4.x*A), h, u4.x*b0);
                h = fmaf(__expf(d4.y*A), h, u4.y*b1);
                h = fmaf(__expf(d4.z*A), h, u4.z*b2);
                h = fmaf(__expf(d4.w*A), h, u4.w*b3);
            }
            for (int tt = q4*4; tt < nt; ++tt) {
                float dA = __expf(dl_t[dl*68 + tt] * A);
                h = fmaf(dA, h, du_t[dl*68 + tt] * xd_t[tt*36 + 20 + s]);
            }
        }
        __syncthreads();
    }
    float v = h * ws[OFF_CLAST + b*16 + s];
    v += __shfl_xor(v, 1); v += __shfl_xor(v, 2);
    v += __shfl_xor(v, 4); v += __shfl_xor(v, 8);
    if (s == 0) ws[OFF_YSCAN + (size_t)b*D_INNER + dg*16 + dl] = v;
}

// ---------- K5: per-batch epilogue: skip + gate + out_proj + MLP head ----------
__global__ __launch_bounds__(320) void k_final(
    const int* __restrict__ idx, const int* __restrict__ tissue_id,
    const int* __restrict__ seq_lengths,
    const float* __restrict__ conv_w, const float* __restrict__ conv_b,
    const float* __restrict__ Dskip, const float* __restrict__ outW,
    const float* __restrict__ p1W, const float* __restrict__ p1b,
    const float* __restrict__ p2W, const float* __restrict__ p2b,
    const float* __restrict__ ws, float* __restrict__ out)
{
    __shared__ float y_l[D_INNER];
    __shared__ float o_l[D_MODEL];
    __shared__ float h1_l[H_OUT];
    int b = blockIdx.x, tid = threadIdx.x;
    int t_last = seq_lengths[b] - 1;
    int tis = tissue_id[b];
    const float* Mseq = ws + OFF_MSEQ;
    const float* Mtis = ws + OFF_MTIS;
    int rows[4];
    #pragma unroll
    for (int k = 0; k < 4; ++k) {
        int t = t_last - 3 + k;
        rows[k] = (t >= 0) ? idx[b*L_ + t] : 0;
    }
    for (int d = tid; d < D_INNER; d += 320) {
        float conv = conv_b[d];
        const float* cw = conv_w + d*4;
        #pragma unroll
        for (int k = 0; k < 4; ++k) {
            int row = rows[k];
            float xz = row ? (Mseq[(size_t)row*1280 + d] + Mtis[(size_t)tis*1280 + d]) : 0.0f;
            conv += cw[k] * xz;
        }
        float u = silu_f(conv);
        int rowL = rows[3];
        float z = rowL ? (Mseq[(size_t)rowL*1280 + 640 + d] + Mtis[(size_t)tis*1280 + 640 + d]) : 0.0f;
        float ys = ws[OFF_YSCAN + (size_t)b*D_INNER + d];
        y_l[d] = (ys + u * Dskip[d]) * silu_f(z);
    }
    __syncthreads();
    if (tid < D_MODEL) {
        const float* w = outW + tid*D_INNER;
        float acc = 0.f;
        #pragma unroll 4
        for (int k = 0; k < D_INNER; k += 4) {
            float4 w4 = *(const float4*)(w + k);
            acc += y_l[k]*w4.x + y_l[k+1]*w4.y + y_l[k+2]*w4.z + y_l[k+3]*w4.w;
        }
        o_l[tid] = acc;
    }
    __syncthreads();
    if (tid < H_OUT) {
        const float* w = p1W + tid*D_MODEL;
        float acc = p1b[tid];
        #pragma unroll 4
        for (int k = 0; k < D_MODEL; k += 4) {
            float4 w4 = *(const float4*)(w + k);
            acc += o_l[k]*w4.x + o_l[k+1]*w4.y + o_l[k+2]*w4.z + o_l[k+3]*w4.w;
        }
        h1_l[tid] = fmaxf(acc, 0.0f);
    }
    __syncthreads();
    if (tid == 0) {
        float acc = p2b[0];
        for (int k = 0; k < H_OUT; ++k) acc += h1_l[k]*p2W[k];
        out[b] = acc;
    }
}

extern "C" void kernel_launch(void* const* d_in, const int* in_sizes, int n_in,
                              void* d_out, int out_size, void* d_ws, size_t ws_size,
                              hipStream_t stream)
{
    const int*   idx   = (const int*)d_in[0];
    const int*   tis   = (const int*)d_in[1];
    const int*   slen  = (const int*)d_in[2];
    const float* seqW  = (const float*)d_in[3];
    const float* tisW  = (const float*)d_in[4];
    const float* inW   = (const float*)d_in[5];
    const float* convw = (const float*)d_in[6];
    const float* convb = (const float*)d_in[7];
    const float* xW    = (const float*)d_in[8];
    const float* dtW   = (const float*)d_in[9];
    const float* dtb   = (const float*)d_in[10];
    const float* Alog  = (const float*)d_in[11];
    const float* Dsk   = (const float*)d_in[12];
    const float* outW  = (const float*)d_in[13];
    const float* p1W   = (const float*)d_in[14];
    const float* p1b   = (const float*)d_in[15];
    const float* p2W   = (const float*)d_in[16];
    const float* p2b   = (const float*)d_in[17];
    float* ws  = (float*)d_ws;
    float* out = (float*)d_out;

    hipLaunchKernelGGL(k_mbuild, dim3(VOCAB + N_TIS, 5), dim3(256), 0, stream, seqW, tisW, inW, ws);
    hipLaunchKernelGGL(k_xdbl,   dim3(L_/TT, B_),        dim3(256), 0, stream,
                       idx, tis, slen, convw, convb, xW, ws);
    hipLaunchKernelGGL(k_scanf,  dim3(D_INNER/16, B_),   dim3(256), 0, stream,
                       idx, tis, slen, convw, convb, dtW, dtb, Alog, ws);
    hipLaunchKernelGGL(k_final,  dim3(B_),               dim3(320), 0, stream,
                       idx, tis, slen, convw, convb, Dsk, outW, p1W, p1b, p2W, p2b, ws, out);
}

// Round 5
// 321.834 us; speedup vs baseline: 1.5979x; 1.2116x over previous
//
#include <hip/hip_runtime.h>
#include <hip/hip_bf16.h>
#include <math.h>

#define B_      16
#define L_      2048
#define D_MODEL 320
#define D_INNER 640
#define D_STATE 16
#define DT_RANK 20
#define H_OUT   128
#define VOCAB   65
#define N_TIS   30
#define TT      16   // t-tile in xdbl producer
#define ST      64   // t-tile in fused scan
#define NCHUNK  8    // scan chunks (256 t each)
#define CHLEN   (L_/NCHUNK)

// workspace layout (floats)
static constexpr size_t OFF_MSEQ  = 0;                          // 65*1280
static constexpr size_t OFF_MTIS  = OFF_MSEQ + VOCAB*1280;      // 30*1280
static constexpr size_t OFF_YSCAN = OFF_MTIS + N_TIS*1280;      // 16*640
static constexpr size_t OFF_CLAST = OFF_YSCAN + B_*D_INNER;     // 16*16
static constexpr size_t OFF_XD    = OFF_CLAST + B_*16;          // B*L*36 (rows 0..19 dt, 20..35 B)
static constexpr size_t OFF_PC    = OFF_XD + (size_t)B_*L_*36;  // B*8*40*256
static constexpr size_t OFF_SC    = OFF_PC + (size_t)B_*NCHUNK*40*256;

__device__ __forceinline__ float silu_f(float x) { return x / (1.0f + __expf(-x)); }

// ---------- A0+A1 fused: renorm embedding row (max_norm=2) then M-row = row @ inW-slice^T ----------
__global__ __launch_bounds__(256) void k_mbuild(
    const float* __restrict__ seqW, const float* __restrict__ tisW,
    const float* __restrict__ inW, float* __restrict__ ws)
{
    __shared__ float a_l[256];
    __shared__ float red[4];
    int v = blockIdx.x, tid = threadIdx.x;
    int K, wofs; const float* src; float* dstM;
    if (v < VOCAB) { K = 256; wofs = 0;   src = seqW + (size_t)v*256;        dstM = ws + OFF_MSEQ + (size_t)v*1280; }
    else           { K = 64;  wofs = 256; src = tisW + (size_t)(v-VOCAB)*64; dstM = ws + OFF_MTIS + (size_t)(v-VOCAB)*1280; }
    float x = (tid < K) ? src[tid] : 0.0f;
    float ss = x * x;
    #pragma unroll
    for (int o = 32; o; o >>= 1) ss += __shfl_xor(ss, o);
    if ((tid & 63) == 0) red[tid >> 6] = ss;
    __syncthreads();
    float tot = red[0] + red[1] + red[2] + red[3];
    float scale = fminf(1.0f, 2.0f / fmaxf(sqrtf(tot), 1e-12f));
    if (tid < K) a_l[tid] = x * scale;
    __syncthreads();

    int j = blockIdx.y * 256 + tid;   // 5*256=1280 columns
    const float* w = inW + (size_t)j*320 + wofs;
    float ac0 = 0.f, ac1 = 0.f, ac2 = 0.f, ac3 = 0.f;
    #pragma unroll 4
    for (int k = 0; k < K; k += 4) {
        float4 w4 = *(const float4*)(w + k);
        ac0 += a_l[k+0]*w4.x; ac1 += a_l[k+1]*w4.y;
        ac2 += a_l[k+2]*w4.z; ac3 += a_l[k+3]*w4.w;
    }
    dstM[j] = (ac0 + ac1) + (ac2 + ac3);
}

// ---------- K2: conv+silu -> x_proj rows 0..35 -> xd[b][t][36]; C rows only at t_last ----------
__global__ __launch_bounds__(256) void k_xdbl(
    const int* __restrict__ idx, const int* __restrict__ tissue_id,
    const int* __restrict__ seq_lengths,
    const float* __restrict__ conv_w, const float* __restrict__ conv_b,
    const float* __restrict__ xW, float* __restrict__ ws)
{
    __shared__ float u_l[TT*641];     // [t][d], stride 641
    __shared__ float xd_l[TT*36];
    __shared__ int   idx_l[TT+3];
    int b = blockIdx.y;
    int t0 = blockIdx.x * TT;
    int t_last = seq_lengths[b] - 1;
    if (t0 > t_last) return;
    int tid = threadIdx.x;
    const float* Mseq = ws + OFF_MSEQ;
    const float* Mtis = ws + OFF_MTIS;
    int tis = tissue_id[b];
    if (tid < TT+3) {
        int t = t0 - 3 + tid;
        idx_l[tid] = (t >= 0) ? idx[b*L_ + t] : 0;
    }
    __syncthreads();

    // phase 1: u = silu(causal depthwise conv4 of xz[:, :640])
    for (int d = tid; d < D_INNER; d += 256) {
        float w0 = conv_w[d*4+0], w1 = conv_w[d*4+1], w2 = conv_w[d*4+2], w3 = conv_w[d*4+3];
        float cb = conv_b[d];
        float mt = Mtis[(size_t)tis*1280 + d];
        auto XZ = [&](int k) -> float {
            int row = idx_l[k];
            return row ? (Mseq[(size_t)row*1280 + d] + mt) : 0.0f;
        };
        float a0 = XZ(0), a1 = XZ(1), a2 = XZ(2);
        for (int t = 0; t < TT; ++t) {
            float a3 = XZ(t+3);
            float c = w0*a0 + w1*a1 + w2*a2 + w3*a3 + cb;
            u_l[t*641 + d] = silu_f(c);
            a0 = a1; a1 = a2; a2 = a3;
        }
    }
    __syncthreads();

    // phase 2: rows 0..35 via 3 passes of 3 rows/wave (wreg[3][10] -> no spill)
    {
        int w = tid >> 6, l = tid & 63;
        #pragma unroll 1
        for (int pass = 0; pass < 3; ++pass) {
            float wreg[3][10];
            #pragma unroll
            for (int kk = 0; kk < 3; ++kk) {
                const float* xr = xW + (size_t)(w + 4*(3*pass + kk))*D_INNER + l;
                #pragma unroll
                for (int i = 0; i < 10; ++i) wreg[kk][i] = xr[64*i];
            }
            for (int t = 0; t < TT; ++t) {
                float ur[10];
                #pragma unroll
                for (int i = 0; i < 10; ++i) ur[i] = u_l[t*641 + l + 64*i];
                #pragma unroll
                for (int kk = 0; kk < 3; ++kk) {
                    float p = 0.f;
                    #pragma unroll
                    for (int i = 0; i < 10; ++i) p = fmaf(wreg[kk][i], ur[i], p);
                    #pragma unroll
                    for (int o = 32; o; o >>= 1) p += __shfl_xor(p, o);
                    if (l == t) xd_l[t*36 + w + 4*(3*pass + kk)] = p;
                }
            }
        }
        // C rows (xW rows 36..51): only t_last is consumed
        if (t_last < t0 + TT) {
            int tl = t_last - t0;
            float ur[10];
            #pragma unroll
            for (int i = 0; i < 10; ++i) ur[i] = u_l[tl*641 + l + 64*i];
            #pragma unroll
            for (int k = 0; k < 4; ++k) {
                const float* xr = xW + (size_t)(36 + w + 4*k)*D_INNER + l;
                float p = 0.f;
                #pragma unroll
                for (int i = 0; i < 10; ++i) p = fmaf(xr[64*i], ur[i], p);
                #pragma unroll
                for (int o = 32; o; o >>= 1) p += __shfl_xor(p, o);
                if (l == 0) ws[OFF_CLAST + b*16 + w + 4*k] = p;
            }
        }
    }
    __syncthreads();

    // write xd tile (coalesced)
    {
        int tmax = min(TT-1, t_last - t0);
        int cnt = (tmax + 1) * 36;
        float* dst = ws + OFF_XD + ((size_t)b*L_ + t0)*36;
        for (int o = tid; o < cnt; o += 256) dst[o] = xd_l[o];
    }
}

// ---------- K3: chunk-parallel fused scan: each block computes (P, S) for one 256-t chunk ----------
// grid (40, B, NCHUNK), block 256. Threads: (dl = tid>>4, s = tid&15).
__global__ __launch_bounds__(256) void k_scanc(
    const int* __restrict__ idx, const int* __restrict__ tissue_id,
    const int* __restrict__ seq_lengths,
    const float* __restrict__ conv_w, const float* __restrict__ conv_b,
    const float* __restrict__ dtW, const float* __restrict__ dtb,
    const float* __restrict__ A_log, float* __restrict__ ws)
{
    __shared__ float xd_t[ST*36];          // [t][36]
    __shared__ float dl_t[16*68];          // [d][t]
    __shared__ float du_t[16*68];
    __shared__ float dtw_l[16*20];
    __shared__ float cw_l[16*4];
    __shared__ float cb_l[16], dtb_l[16], mt_l[16];
    __shared__ int   idx_t[ST+3];

    int b = blockIdx.y, dg = blockIdx.x, c = blockIdx.z;
    int t_last = seq_lengths[b] - 1;
    int t_begin = c * CHLEN;
    if (t_begin > t_last) return;           // combine skips this chunk
    int t_end = min(t_begin + CHLEN - 1, t_last);
    int tid = threadIdx.x;
    int dl = tid >> 4, s = tid & 15;
    int tis = tissue_id[b];
    const float* Mseq = ws + OFF_MSEQ;

    if (tid < 16) {
        int d = dg*16 + tid;
        cb_l[tid]  = conv_b[d];
        dtb_l[tid] = dtb[d];
        mt_l[tid]  = ws[OFF_MTIS + (size_t)tis*1280 + d];
    }
    if (tid < 64) {
        int dd = tid >> 2, k = tid & 3;
        cw_l[dd*4 + k] = conv_w[(dg*16 + dd)*4 + k];
    }
    for (int o = tid; o < 16*20; o += 256) {
        int dd = o / 20, r = o % 20;
        dtw_l[o] = dtW[(dg*16 + dd)*20 + r];
    }
    float A = -__expf(A_log[(dg*16 + dl)*D_STATE + s]);

    float h = 0.0f;     // chunk-local S
    float sd = 0.0f;    // sum of delta over chunk (per d; duplicated across s)
    for (int t0 = t_begin; t0 <= t_end; t0 += ST) {
        int nt = min(ST, t_end - t0 + 1);
        if (tid < ST+3) {
            int t = t0 - 3 + tid;
            idx_t[tid] = (t >= 0 && t < L_) ? idx[b*L_ + t] : 0;
        }
        {
            const float* src = ws + OFF_XD + ((size_t)b*L_ + t0)*36;
            int cnt = nt * 36;
            for (int o = tid; o < cnt; o += 256) xd_t[o] = src[o];
        }
        __syncthreads();

        // produce delta / du for 16 d x nt t: thread = (tt = tid>>2, 4 consecutive d)
        {
            int tt = tid >> 2, dd0 = (tid & 3) * 4;
            if (tt < nt) {
                float cc0 = cb_l[dd0+0], cc1 = cb_l[dd0+1], cc2 = cb_l[dd0+2], cc3 = cb_l[dd0+3];
                #pragma unroll
                for (int k = 0; k < 4; ++k) {
                    int row = idx_t[tt + k];
                    float4 m;
                    if (row) {
                        m = *(const float4*)(Mseq + (size_t)row*1280 + dg*16 + dd0);
                        m.x += mt_l[dd0+0]; m.y += mt_l[dd0+1];
                        m.z += mt_l[dd0+2]; m.w += mt_l[dd0+3];
                    } else m = make_float4(0.f,0.f,0.f,0.f);
                    cc0 = fmaf(cw_l[(dd0+0)*4+k], m.x, cc0);
                    cc1 = fmaf(cw_l[(dd0+1)*4+k], m.y, cc1);
                    cc2 = fmaf(cw_l[(dd0+2)*4+k], m.z, cc2);
                    cc3 = fmaf(cw_l[(dd0+3)*4+k], m.w, cc3);
                }
                float uu[4] = { silu_f(cc0), silu_f(cc1), silu_f(cc2), silu_f(cc3) };
                float xdr[20];
                #pragma unroll
                for (int r = 0; r < 20; ++r) xdr[r] = xd_t[tt*36 + r];
                #pragma unroll
                for (int i = 0; i < 4; ++i) {
                    int d = dd0 + i;
                    float x = dtb_l[d];
                    #pragma unroll
                    for (int r = 0; r < 20; ++r) x = fmaf(xdr[r], dtw_l[d*20 + r], x);
                    float sp = fmaxf(x, 0.0f) + log1pf(__expf(-fabsf(x)));
                    dl_t[d*68 + tt] = sp;
                    du_t[d*68 + tt] = sp * uu[i];
                }
            }
        }
        __syncthreads();

        // recurrence (chunk-local) + delta accumulation
        {
            int q4 = nt >> 2;
            for (int q = 0; q < q4; ++q) {
                float4 d4 = *(const float4*)(dl_t + dl*68 + 4*q);
                float4 u4 = *(const float4*)(du_t + dl*68 + 4*q);
                float b0 = xd_t[(4*q+0)*36 + 20 + s];
                float b1 = xd_t[(4*q+1)*36 + 20 + s];
                float b2 = xd_t[(4*q+2)*36 + 20 + s];
                float b3 = xd_t[(4*q+3)*36 + 20 + s];
                h = fmaf(__expf(d4.x*A), h, u4.x*b0);
                h = fmaf(__expf(d4.y*A), h, u4.y*b1);
                h = fmaf(__expf(d4.z*A), h, u4.z*b2);
                h = fmaf(__expf(d4.w*A), h, u4.w*b3);
                sd += (d4.x + d4.y) + (d4.z + d4.w);
            }
            for (int tt = q4*4; tt < nt; ++tt) {
                float dlt = dl_t[dl*68 + tt];
                h = fmaf(__expf(dlt * A), h, du_t[dl*68 + tt] * xd_t[tt*36 + 20 + s]);
                sd += dlt;
            }
        }
        __syncthreads();
    }
    float P = __expf(A * sd);
    size_t base = (((size_t)b*NCHUNK + c)*40 + dg)*256 + tid;
    ws[OFF_PC + base] = P;
    ws[OFF_SC + base] = h;
}

// ---------- K3b: combine chunk transfers, apply C_last, reduce over s ----------
__global__ __launch_bounds__(256) void k_comb(const int* __restrict__ seq_lengths,
                                              float* __restrict__ ws)
{
    int b = blockIdx.y, dg = blockIdx.x;
    int tid = threadIdx.x;
    int dl = tid >> 4, s = tid & 15;
    int t_last = seq_lengths[b] - 1;
    int ncv = t_last / CHLEN + 1;
    float h = 0.0f;
    for (int c = 0; c < ncv; ++c) {
        size_t base = (((size_t)b*NCHUNK + c)*40 + dg)*256 + tid;
        h = fmaf(ws[OFF_PC + base], h, ws[OFF_SC + base]);
    }
    float v = h * ws[OFF_CLAST + b*16 + s];
    v += __shfl_xor(v, 1); v += __shfl_xor(v, 2);
    v += __shfl_xor(v, 4); v += __shfl_xor(v, 8);
    if (s == 0) ws[OFF_YSCAN + (size_t)b*D_INNER + dg*16 + dl] = v;
}

// ---------- K5: per-batch epilogue: skip + gate + out_proj + MLP head ----------
__global__ __launch_bounds__(320) void k_final(
    const int* __restrict__ idx, const int* __restrict__ tissue_id,
    const int* __restrict__ seq_lengths,
    const float* __restrict__ conv_w, const float* __restrict__ conv_b,
    const float* __restrict__ Dskip, const float* __restrict__ outW,
    const float* __restrict__ p1W, const float* __restrict__ p1b,
    const float* __restrict__ p2W, const float* __restrict__ p2b,
    const float* __restrict__ ws, float* __restrict__ out)
{
    __shared__ float y_l[D_INNER];
    __shared__ float o_l[D_MODEL];
    __shared__ float h1_l[H_OUT];
    int b = blockIdx.x, tid = threadIdx.x;
    int t_last = seq_lengths[b] - 1;
    int tis = tissue_id[b];
    const float* Mseq = ws + OFF_MSEQ;
    const float* Mtis = ws + OFF_MTIS;
    int rows[4];
    #pragma unroll
    for (int k = 0; k < 4; ++k) {
        int t = t_last - 3 + k;
        rows[k] = (t >= 0) ? idx[b*L_ + t] : 0;
    }
    for (int d = tid; d < D_INNER; d += 320) {
        float conv = conv_b[d];
        const float* cw = conv_w + d*4;
        #pragma unroll
        for (int k = 0; k < 4; ++k) {
            int row = rows[k];
            float xz = row ? (Mseq[(size_t)row*1280 + d] + Mtis[(size_t)tis*1280 + d]) : 0.0f;
            conv += cw[k] * xz;
        }
        float u = silu_f(conv);
        int rowL = rows[3];
        float z = rowL ? (Mseq[(size_t)rowL*1280 + 640 + d] + Mtis[(size_t)tis*1280 + 640 + d]) : 0.0f;
        float ys = ws[OFF_YSCAN + (size_t)b*D_INNER + d];
        y_l[d] = (ys + u * Dskip[d]) * silu_f(z);
    }
    __syncthreads();
    if (tid < D_MODEL) {
        const float* w = outW + tid*D_INNER;
        float acc = 0.f;
        #pragma unroll 4
        for (int k = 0; k < D_INNER; k += 4) {
            float4 w4 = *(const float4*)(w + k);
            acc += y_l[k]*w4.x + y_l[k+1]*w4.y + y_l[k+2]*w4.z + y_l[k+3]*w4.w;
        }
        o_l[tid] = acc;
    }
    __syncthreads();
    if (tid < H_OUT) {
        const float* w = p1W + tid*D_MODEL;
        float acc = p1b[tid];
        #pragma unroll 4
        for (int k = 0; k < D_MODEL; k += 4) {
            float4 w4 = *(const float4*)(w + k);
            acc += o_l[k]*w4.x + o_l[k+1]*w4.y + o_l[k+2]*w4.z + o_l[k+3]*w4.w;
        }
        h1_l[tid] = fmaxf(acc, 0.0f);
    }
    __syncthreads();
    if (tid == 0) {
        float acc = p2b[0];
        for (int k = 0; k < H_OUT; ++k) acc += h1_l[k]*p2W[k];
        out[b] = acc;
    }
}

extern "C" void kernel_launch(void* const* d_in, const int* in_sizes, int n_in,
                              void* d_out, int out_size, void* d_ws, size_t ws_size,
                              hipStream_t stream)
{
    const int*   idx   = (const int*)d_in[0];
    const int*   tis   = (const int*)d_in[1];
    const int*   slen  = (const int*)d_in[2];
    const float* seqW  = (const float*)d_in[3];
    const float* tisW  = (const float*)d_in[4];
    const float* inW   = (const float*)d_in[5];
    const float* convw = (const float*)d_in[6];
    const float* convb = (const float*)d_in[7];
    const float* xW    = (const float*)d_in[8];
    const float* dtW   = (const float*)d_in[9];
    const float* dtb   = (const float*)d_in[10];
    const float* Alog  = (const float*)d_in[11];
    const float* Dsk   = (const float*)d_in[12];
    const float* outW  = (const float*)d_in[13];
    const float* p1W   = (const float*)d_in[14];
    const float* p1b   = (const float*)d_in[15];
    const float* p2W   = (const float*)d_in[16];
    const float* p2b   = (const float*)d_in[17];
    float* ws  = (float*)d_ws;
    float* out = (float*)d_out;

    hipLaunchKernelGGL(k_mbuild, dim3(VOCAB + N_TIS, 5), dim3(256), 0, stream, seqW, tisW, inW, ws);
    hipLaunchKernelGGL(k_xdbl,   dim3(L_/TT, B_),        dim3(256), 0, stream,
                       idx, tis, slen, convw, convb, xW, ws);
    hipLaunchKernelGGL(k_scanc,  dim3(D_INNER/16, B_, NCHUNK), dim3(256), 0, stream,
                       idx, tis, slen, convw, convb, dtW, dtb, Alog, ws);
    hipLaunchKernelGGL(k_comb,   dim3(D_INNER/16, B_),   dim3(256), 0, stream, slen, ws);
    hipLaunchKernelGGL(k_final,  dim3(B_),               dim3(320), 0, stream,
                       idx, tis, slen, convw, convb, Dsk, outW, p1W, p1b, p2W, p2b, ws, out);
}

// Round 6
// 298.777 us; speedup vs baseline: 1.7213x; 1.0772x over previous
//
#include <hip/hip_runtime.h>
#include <hip/hip_bf16.h>
#include <math.h>

#define B_      16
#define L_      2048
#define D_MODEL 320
#define D_INNER 640
#define D_STATE 16
#define DT_RANK 20
#define H_OUT   128
#define VOCAB   65
#define N_TIS   30
#define TT      8    // t-tile in xdbl producer (16->8: LDS 41->21 KB, 2x blocks)
#define ST      64   // t-tile in fused scan
#define NCHUNK  16   // scan chunks (128 t each)
#define CHLEN   (L_/NCHUNK)

// workspace layout (floats)
static constexpr size_t OFF_MSEQ  = 0;                          // 65*1280
static constexpr size_t OFF_MTIS  = OFF_MSEQ + VOCAB*1280;      // 30*1280
static constexpr size_t OFF_YSCAN = OFF_MTIS + N_TIS*1280;      // 16*640
static constexpr size_t OFF_CLAST = OFF_YSCAN + B_*D_INNER;     // 16*16
static constexpr size_t OFF_XD    = OFF_CLAST + B_*16;          // B*L*36 (rows 0..19 dt, 20..35 B)
static constexpr size_t OFF_PC    = OFF_XD + (size_t)B_*L_*36;  // B*NCHUNK*40*256
static constexpr size_t OFF_SC    = OFF_PC + (size_t)B_*NCHUNK*40*256;

__device__ __forceinline__ float silu_f(float x) { return x / (1.0f + __expf(-x)); }

// ---------- A0+A1 fused: renorm embedding row (max_norm=2) then M-row = row @ inW-slice^T ----------
__global__ __launch_bounds__(256) void k_mbuild(
    const float* __restrict__ seqW, const float* __restrict__ tisW,
    const float* __restrict__ inW, float* __restrict__ ws)
{
    __shared__ float a_l[256];
    __shared__ float red[4];
    int v = blockIdx.x, tid = threadIdx.x;
    int K, wofs; const float* src; float* dstM;
    if (v < VOCAB) { K = 256; wofs = 0;   src = seqW + (size_t)v*256;        dstM = ws + OFF_MSEQ + (size_t)v*1280; }
    else           { K = 64;  wofs = 256; src = tisW + (size_t)(v-VOCAB)*64; dstM = ws + OFF_MTIS + (size_t)(v-VOCAB)*1280; }
    float x = (tid < K) ? src[tid] : 0.0f;
    float ss = x * x;
    #pragma unroll
    for (int o = 32; o; o >>= 1) ss += __shfl_xor(ss, o);
    if ((tid & 63) == 0) red[tid >> 6] = ss;
    __syncthreads();
    float tot = red[0] + red[1] + red[2] + red[3];
    float scale = fminf(1.0f, 2.0f / fmaxf(sqrtf(tot), 1e-12f));
    if (tid < K) a_l[tid] = x * scale;
    __syncthreads();

    int j = blockIdx.y * 256 + tid;   // 5*256=1280 columns
    const float* w = inW + (size_t)j*320 + wofs;
    float ac0 = 0.f, ac1 = 0.f, ac2 = 0.f, ac3 = 0.f;
    #pragma unroll 4
    for (int k = 0; k < K; k += 4) {
        float4 w4 = *(const float4*)(w + k);
        ac0 += a_l[k+0]*w4.x; ac1 += a_l[k+1]*w4.y;
        ac2 += a_l[k+2]*w4.z; ac3 += a_l[k+3]*w4.w;
    }
    dstM[j] = (ac0 + ac1) + (ac2 + ac3);
}

// ---------- K2: conv+silu -> x_proj rows 0..35 -> xd[b][t][36]; C rows only at t_last ----------
__global__ __launch_bounds__(256) void k_xdbl(
    const int* __restrict__ idx, const int* __restrict__ tissue_id,
    const int* __restrict__ seq_lengths,
    const float* __restrict__ conv_w, const float* __restrict__ conv_b,
    const float* __restrict__ xW, float* __restrict__ ws)
{
    __shared__ float u_l[TT*641];     // [t][d], stride 641  (~21 KB at TT=8)
    __shared__ float xd_l[TT*36];
    __shared__ int   idx_l[TT+3];
    int b = blockIdx.y;
    int t0 = blockIdx.x * TT;
    int t_last = seq_lengths[b] - 1;
    if (t0 > t_last) return;
    int tid = threadIdx.x;
    const float* Mseq = ws + OFF_MSEQ;
    const float* Mtis = ws + OFF_MTIS;
    int tis = tissue_id[b];
    if (tid < TT+3) {
        int t = t0 - 3 + tid;
        idx_l[tid] = (t >= 0) ? idx[b*L_ + t] : 0;
    }
    __syncthreads();

    // phase 1: u = silu(causal depthwise conv4 of xz[:, :640])
    for (int d = tid; d < D_INNER; d += 256) {
        float w0 = conv_w[d*4+0], w1 = conv_w[d*4+1], w2 = conv_w[d*4+2], w3 = conv_w[d*4+3];
        float cb = conv_b[d];
        float mt = Mtis[(size_t)tis*1280 + d];
        auto XZ = [&](int k) -> float {
            int row = idx_l[k];
            return row ? (Mseq[(size_t)row*1280 + d] + mt) : 0.0f;
        };
        float a0 = XZ(0), a1 = XZ(1), a2 = XZ(2);
        for (int t = 0; t < TT; ++t) {
            float a3 = XZ(t+3);
            float c = w0*a0 + w1*a1 + w2*a2 + w3*a3 + cb;
            u_l[t*641 + d] = silu_f(c);
            a0 = a1; a1 = a2; a2 = a3;
        }
    }
    __syncthreads();

    // phase 2: rows 0..35 via 3 passes of 3 rows/wave (wreg[3][10] -> no spill)
    {
        int w = tid >> 6, l = tid & 63;
        #pragma unroll 1
        for (int pass = 0; pass < 3; ++pass) {
            float wreg[3][10];
            #pragma unroll
            for (int kk = 0; kk < 3; ++kk) {
                const float* xr = xW + (size_t)(w + 4*(3*pass + kk))*D_INNER + l;
                #pragma unroll
                for (int i = 0; i < 10; ++i) wreg[kk][i] = xr[64*i];
            }
            for (int t = 0; t < TT; ++t) {
                float ur[10];
                #pragma unroll
                for (int i = 0; i < 10; ++i) ur[i] = u_l[t*641 + l + 64*i];
                #pragma unroll
                for (int kk = 0; kk < 3; ++kk) {
                    float p = 0.f;
                    #pragma unroll
                    for (int i = 0; i < 10; ++i) p = fmaf(wreg[kk][i], ur[i], p);
                    #pragma unroll
                    for (int o = 32; o; o >>= 1) p += __shfl_xor(p, o);
                    if (l == t) xd_l[t*36 + w + 4*(3*pass + kk)] = p;
                }
            }
        }
        // C rows (xW rows 36..51): only t_last is consumed
        if (t_last < t0 + TT) {
            int tl = t_last - t0;
            float ur[10];
            #pragma unroll
            for (int i = 0; i < 10; ++i) ur[i] = u_l[tl*641 + l + 64*i];
            #pragma unroll
            for (int k = 0; k < 4; ++k) {
                const float* xr = xW + (size_t)(36 + w + 4*k)*D_INNER + l;
                float p = 0.f;
                #pragma unroll
                for (int i = 0; i < 10; ++i) p = fmaf(xr[64*i], ur[i], p);
                #pragma unroll
                for (int o = 32; o; o >>= 1) p += __shfl_xor(p, o);
                if (l == 0) ws[OFF_CLAST + b*16 + w + 4*k] = p;
            }
        }
    }
    __syncthreads();

    // write xd tile (coalesced)
    {
        int tmax = min(TT-1, t_last - t0);
        int cnt = (tmax + 1) * 36;
        float* dst = ws + OFF_XD + ((size_t)b*L_ + t0)*36;
        for (int o = tid; o < cnt; o += 256) dst[o] = xd_l[o];
    }
}

// ---------- K3: chunk-parallel fused scan: each block computes (P, S) for one 128-t chunk ----------
// grid (40, B, NCHUNK), block 256. Threads: (dl = tid>>4, s = tid&15).
__global__ __launch_bounds__(256) void k_scanc(
    const int* __restrict__ idx, const int* __restrict__ tissue_id,
    const int* __restrict__ seq_lengths,
    const float* __restrict__ conv_w, const float* __restrict__ conv_b,
    const float* __restrict__ dtW, const float* __restrict__ dtb,
    const float* __restrict__ A_log, float* __restrict__ ws)
{
    __shared__ float xd_t[ST*36];          // [t][36]
    __shared__ float dl_t[16*68];          // [d][t]
    __shared__ float du_t[16*68];
    __shared__ float dtw_l[16*20];
    __shared__ float cw_l[16*4];
    __shared__ float cb_l[16], dtb_l[16], mt_l[16];
    __shared__ int   idx_t[ST+3];

    int b = blockIdx.y, dg = blockIdx.x, c = blockIdx.z;
    int t_last = seq_lengths[b] - 1;
    int t_begin = c * CHLEN;
    if (t_begin > t_last) return;           // combine skips this chunk
    int t_end = min(t_begin + CHLEN - 1, t_last);
    int tid = threadIdx.x;
    int dl = tid >> 4, s = tid & 15;
    int tis = tissue_id[b];
    const float* Mseq = ws + OFF_MSEQ;

    if (tid < 16) {
        int d = dg*16 + tid;
        cb_l[tid]  = conv_b[d];
        dtb_l[tid] = dtb[d];
        mt_l[tid]  = ws[OFF_MTIS + (size_t)tis*1280 + d];
    }
    if (tid < 64) {
        int dd = tid >> 2, k = tid & 3;
        cw_l[dd*4 + k] = conv_w[(dg*16 + dd)*4 + k];
    }
    for (int o = tid; o < 16*20; o += 256) {
        int dd = o / 20, r = o % 20;
        dtw_l[o] = dtW[(dg*16 + dd)*20 + r];
    }
    float A = -__expf(A_log[(dg*16 + dl)*D_STATE + s]);

    float h = 0.0f;     // chunk-local S
    float sd = 0.0f;    // sum of delta over chunk (per d; duplicated across s)
    for (int t0 = t_begin; t0 <= t_end; t0 += ST) {
        int nt = min(ST, t_end - t0 + 1);
        if (tid < ST+3) {
            int t = t0 - 3 + tid;
            idx_t[tid] = (t >= 0 && t < L_) ? idx[b*L_ + t] : 0;
        }
        {
            const float* src = ws + OFF_XD + ((size_t)b*L_ + t0)*36;
            int cnt = nt * 36;
            for (int o = tid; o < cnt; o += 256) xd_t[o] = src[o];
        }
        __syncthreads();

        // produce delta / du for 16 d x nt t: thread = (tt = tid>>2, 4 consecutive d)
        {
            int tt = tid >> 2, dd0 = (tid & 3) * 4;
            if (tt < nt) {
                float cc0 = cb_l[dd0+0], cc1 = cb_l[dd0+1], cc2 = cb_l[dd0+2], cc3 = cb_l[dd0+3];
                #pragma unroll
                for (int k = 0; k < 4; ++k) {
                    int row = idx_t[tt + k];
                    float4 m;
                    if (row) {
                        m = *(const float4*)(Mseq + (size_t)row*1280 + dg*16 + dd0);
                        m.x += mt_l[dd0+0]; m.y += mt_l[dd0+1];
                        m.z += mt_l[dd0+2]; m.w += mt_l[dd0+3];
                    } else m = make_float4(0.f,0.f,0.f,0.f);
                    cc0 = fmaf(cw_l[(dd0+0)*4+k], m.x, cc0);
                    cc1 = fmaf(cw_l[(dd0+1)*4+k], m.y, cc1);
                    cc2 = fmaf(cw_l[(dd0+2)*4+k], m.z, cc2);
                    cc3 = fmaf(cw_l[(dd0+3)*4+k], m.w, cc3);
                }
                float uu[4] = { silu_f(cc0), silu_f(cc1), silu_f(cc2), silu_f(cc3) };
                float xdr[20];
                #pragma unroll
                for (int r = 0; r < 20; ++r) xdr[r] = xd_t[tt*36 + r];
                #pragma unroll
                for (int i = 0; i < 4; ++i) {
                    int d = dd0 + i;
                    float x = dtb_l[d];
                    #pragma unroll
                    for (int r = 0; r < 20; ++r) x = fmaf(xdr[r], dtw_l[d*20 + r], x);
                    float sp = fmaxf(x, 0.0f) + log1pf(__expf(-fabsf(x)));
                    dl_t[d*68 + tt] = sp;
                    du_t[d*68 + tt] = sp * uu[i];
                }
            }
        }
        __syncthreads();

        // recurrence (chunk-local) + delta accumulation
        {
            int q4 = nt >> 2;
            for (int q = 0; q < q4; ++q) {
                float4 d4 = *(const float4*)(dl_t + dl*68 + 4*q);
                float4 u4 = *(const float4*)(du_t + dl*68 + 4*q);
                float b0 = xd_t[(4*q+0)*36 + 20 + s];
                float b1 = xd_t[(4*q+1)*36 + 20 + s];
                float b2 = xd_t[(4*q+2)*36 + 20 + s];
                float b3 = xd_t[(4*q+3)*36 + 20 + s];
                h = fmaf(__expf(d4.x*A), h, u4.x*b0);
                h = fmaf(__expf(d4.y*A), h, u4.y*b1);
                h = fmaf(__expf(d4.z*A), h, u4.z*b2);
                h = fmaf(__expf(d4.w*A), h, u4.w*b3);
                sd += (d4.x + d4.y) + (d4.z + d4.w);
            }
            for (int tt = q4*4; tt < nt; ++tt) {
                float dlt = dl_t[dl*68 + tt];
                h = fmaf(__expf(dlt * A), h, du_t[dl*68 + tt] * xd_t[tt*36 + 20 + s]);
                sd += dlt;
            }
        }
        __syncthreads();
    }
    float P = __expf(A * sd);
    size_t base = (((size_t)b*NCHUNK + c)*40 + dg)*256 + tid;
    ws[OFF_PC + base] = P;
    ws[OFF_SC + base] = h;
}

// ---------- K3b: combine chunk transfers, apply C_last, reduce over s ----------
__global__ __launch_bounds__(256) void k_comb(const int* __restrict__ seq_lengths,
                                              float* __restrict__ ws)
{
    int b = blockIdx.y, dg = blockIdx.x;
    int tid = threadIdx.x;
    int dl = tid >> 4, s = tid & 15;
    int t_last = seq_lengths[b] - 1;
    int ncv = t_last / CHLEN + 1;
    float h = 0.0f;
    for (int c = 0; c < ncv; ++c) {
        size_t base = (((size_t)b*NCHUNK + c)*40 + dg)*256 + tid;
        h = fmaf(ws[OFF_PC + base], h, ws[OFF_SC + base]);
    }
    float v = h * ws[OFF_CLAST + b*16 + s];
    v += __shfl_xor(v, 1); v += __shfl_xor(v, 2);
    v += __shfl_xor(v, 4); v += __shfl_xor(v, 8);
    if (s == 0) ws[OFF_YSCAN + (size_t)b*D_INNER + dg*16 + dl] = v;
}

// ---------- K5: per-batch epilogue: skip + gate + out_proj + MLP head ----------
__global__ __launch_bounds__(320) void k_final(
    const int* __restrict__ idx, const int* __restrict__ tissue_id,
    const int* __restrict__ seq_lengths,
    const float* __restrict__ conv_w, const float* __restrict__ conv_b,
    const float* __restrict__ Dskip, const float* __restrict__ outW,
    const float* __restrict__ p1W, const float* __restrict__ p1b,
    const float* __restrict__ p2W, const float* __restrict__ p2b,
    const float* __restrict__ ws, float* __restrict__ out)
{
    __shared__ float y_l[D_INNER];
    __shared__ float o_l[D_MODEL];
    __shared__ float h1_l[H_OUT];
    int b = blockIdx.x, tid = threadIdx.x;
    int t_last = seq_lengths[b] - 1;
    int tis = tissue_id[b];
    const float* Mseq = ws + OFF_MSEQ;
    const float* Mtis = ws + OFF_MTIS;
    int rows[4];
    #pragma unroll
    for (int k = 0; k < 4; ++k) {
        int t = t_last - 3 + k;
        rows[k] = (t >= 0) ? idx[b*L_ + t] : 0;
    }
    for (int d = tid; d < D_INNER; d += 320) {
        float conv = conv_b[d];
        const float* cw = conv_w + d*4;
        #pragma unroll
        for (int k = 0; k < 4; ++k) {
            int row = rows[k];
            float xz = row ? (Mseq[(size_t)row*1280 + d] + Mtis[(size_t)tis*1280 + d]) : 0.0f;
            conv += cw[k] * xz;
        }
        float u = silu_f(conv);
        int rowL = rows[3];
        float z = rowL ? (Mseq[(size_t)rowL*1280 + 640 + d] + Mtis[(size_t)tis*1280 + 640 + d]) : 0.0f;
        float ys = ws[OFF_YSCAN + (size_t)b*D_INNER + d];
        y_l[d] = (ys + u * Dskip[d]) * silu_f(z);
    }
    __syncthreads();
    if (tid < D_MODEL) {
        const float* w = outW + tid*D_INNER;
        float acc = 0.f;
        #pragma unroll 4
        for (int k = 0; k < D_INNER; k += 4) {
            float4 w4 = *(const float4*)(w + k);
            acc += y_l[k]*w4.x + y_l[k+1]*w4.y + y_l[k+2]*w4.z + y_l[k+3]*w4.w;
        }
        o_l[tid] = acc;
    }
    __syncthreads();
    if (tid < H_OUT) {
        const float* w = p1W + tid*D_MODEL;
        float acc = p1b[tid];
        #pragma unroll 4
        for (int k = 0; k < D_MODEL; k += 4) {
            float4 w4 = *(const float4*)(w + k);
            acc += o_l[k]*w4.x + o_l[k+1]*w4.y + o_l[k+2]*w4.z + o_l[k+3]*w4.w;
        }
        h1_l[tid] = fmaxf(acc, 0.0f);
    }
    __syncthreads();
    if (tid == 0) {
        float acc = p2b[0];
        for (int k = 0; k < H_OUT; ++k) acc += h1_l[k]*p2W[k];
        out[b] = acc;
    }
}

extern "C" void kernel_launch(void* const* d_in, const int* in_sizes, int n_in,
                              void* d_out, int out_size, void* d_ws, size_t ws_size,
                              hipStream_t stream)
{
    const int*   idx   = (const int*)d_in[0];
    const int*   tis   = (const int*)d_in[1];
    const int*   slen  = (const int*)d_in[2];
    const float* seqW  = (const float*)d_in[3];
    const float* tisW  = (const float*)d_in[4];
    const float* inW   = (const float*)d_in[5];
    const float* convw = (const float*)d_in[6];
    const float* convb = (const float*)d_in[7];
    const float* xW    = (const float*)d_in[8];
    const float* dtW   = (const float*)d_in[9];
    const float* dtb   = (const float*)d_in[10];
    const float* Alog  = (const float*)d_in[11];
    const float* Dsk   = (const float*)d_in[12];
    const float* outW  = (const float*)d_in[13];
    const float* p1W   = (const float*)d_in[14];
    const float* p1b   = (const float*)d_in[15];
    const float* p2W   = (const float*)d_in[16];
    const float* p2b   = (const float*)d_in[17];
    float* ws  = (float*)d_ws;
    float* out = (float*)d_out;

    hipLaunchKernelGGL(k_mbuild, dim3(VOCAB + N_TIS, 5), dim3(256), 0, stream, seqW, tisW, inW, ws);
    hipLaunchKernelGGL(k_xdbl,   dim3(L_/TT, B_),        dim3(256), 0, stream,
                       idx, tis, slen, convw, convb, xW, ws);
    hipLaunchKernelGGL(k_scanc,  dim3(D_INNER/16, B_, NCHUNK), dim3(256), 0, stream,
                       idx, tis, slen, convw, convb, dtW, dtb, Alog, ws);
    hipLaunchKernelGGL(k_comb,   dim3(D_INNER/16, B_),   dim3(256), 0, stream, slen, ws);
    hipLaunchKernelGGL(k_final,  dim3(B_),               dim3(320), 0, stream,
                       idx, tis, slen, convw, convb, Dsk, outW, p1W, p1b, p2W, p2b, ws, out);
}

// Round 7
// 295.412 us; speedup vs baseline: 1.7409x; 1.0114x over previous
//
#include <hip/hip_runtime.h>
#include <hip/hip_bf16.h>
#include <math.h>

#define B_      16
#define L_      2048
#define D_MODEL 320
#define D_INNER 640
#define D_STATE 16
#define DT_RANK 20
#define H_OUT   128
#define VOCAB   65
#define N_TIS   30
#define TT      8    // t-tile in xdbl producer
#define ST      64   // t-tile in fused scan
#define NCHUNK  16   // scan chunks (128 t each)
#define CHLEN   (L_/NCHUNK)

// workspace layout (floats)
static constexpr size_t OFF_MSEQ  = 0;                          // 65*1280
static constexpr size_t OFF_MTIS  = OFF_MSEQ + VOCAB*1280;      // 30*1280
static constexpr size_t OFF_YSCAN = OFF_MTIS + N_TIS*1280;      // 16*640 (unused now)
static constexpr size_t OFF_CLAST = OFF_YSCAN + B_*D_INNER;     // 16*16
static constexpr size_t OFF_XD    = OFF_CLAST + B_*16;          // B*L*36 (rows 0..19 dt, 20..35 B)
static constexpr size_t OFF_PC    = OFF_XD + (size_t)B_*L_*36;  // B*NCHUNK*40*256
static constexpr size_t OFF_SC    = OFF_PC + (size_t)B_*NCHUNK*40*256;

__device__ __forceinline__ float silu_f(float x) { return x / (1.0f + __expf(-x)); }

// ---------- A0+A1 fused: renorm embedding row (max_norm=2) then M-row = row @ inW-slice^T ----------
__global__ __launch_bounds__(256) void k_mbuild(
    const float* __restrict__ seqW, const float* __restrict__ tisW,
    const float* __restrict__ inW, float* __restrict__ ws)
{
    __shared__ float a_l[256];
    __shared__ float red[4];
    int v = blockIdx.x, tid = threadIdx.x;
    int K, wofs; const float* src; float* dstM;
    if (v < VOCAB) { K = 256; wofs = 0;   src = seqW + (size_t)v*256;        dstM = ws + OFF_MSEQ + (size_t)v*1280; }
    else           { K = 64;  wofs = 256; src = tisW + (size_t)(v-VOCAB)*64; dstM = ws + OFF_MTIS + (size_t)(v-VOCAB)*1280; }
    float x = (tid < K) ? src[tid] : 0.0f;
    float ss = x * x;
    #pragma unroll
    for (int o = 32; o; o >>= 1) ss += __shfl_xor(ss, o);
    if ((tid & 63) == 0) red[tid >> 6] = ss;
    __syncthreads();
    float tot = red[0] + red[1] + red[2] + red[3];
    float scale = fminf(1.0f, 2.0f / fmaxf(sqrtf(tot), 1e-12f));
    if (tid < K) a_l[tid] = x * scale;
    __syncthreads();

    int j = blockIdx.y * 256 + tid;
    const float* w = inW + (size_t)j*320 + wofs;
    float ac0 = 0.f, ac1 = 0.f, ac2 = 0.f, ac3 = 0.f;
    #pragma unroll 4
    for (int k = 0; k < K; k += 4) {
        float4 w4 = *(const float4*)(w + k);
        ac0 += a_l[k+0]*w4.x; ac1 += a_l[k+1]*w4.y;
        ac2 += a_l[k+2]*w4.z; ac3 += a_l[k+3]*w4.w;
    }
    dstM[j] = (ac0 + ac1) + (ac2 + ac3);
}

// ---------- K2: conv+silu -> x_proj rows 0..35 -> xd[b][t][36]; C rows only at t_last ----------
__global__ __launch_bounds__(256) void k_xdbl(
    const int* __restrict__ idx, const int* __restrict__ tissue_id,
    const int* __restrict__ seq_lengths,
    const float* __restrict__ conv_w, const float* __restrict__ conv_b,
    const float* __restrict__ xW, float* __restrict__ ws)
{
    __shared__ float u_l[TT*641];
    __shared__ float xd_l[TT*36];
    __shared__ int   idx_l[TT+3];
    int b = blockIdx.y;
    int t0 = blockIdx.x * TT;
    int t_last = seq_lengths[b] - 1;
    if (t0 > t_last) return;
    int tid = threadIdx.x;
    const float* Mseq = ws + OFF_MSEQ;
    const float* Mtis = ws + OFF_MTIS;
    int tis = tissue_id[b];
    if (tid < TT+3) {
        int t = t0 - 3 + tid;
        idx_l[tid] = (t >= 0) ? idx[b*L_ + t] : 0;
    }
    __syncthreads();

    for (int d = tid; d < D_INNER; d += 256) {
        float w0 = conv_w[d*4+0], w1 = conv_w[d*4+1], w2 = conv_w[d*4+2], w3 = conv_w[d*4+3];
        float cb = conv_b[d];
        float mt = Mtis[(size_t)tis*1280 + d];
        auto XZ = [&](int k) -> float {
            int row = idx_l[k];
            return row ? (Mseq[(size_t)row*1280 + d] + mt) : 0.0f;
        };
        float a0 = XZ(0), a1 = XZ(1), a2 = XZ(2);
        for (int t = 0; t < TT; ++t) {
            float a3 = XZ(t+3);
            float c = w0*a0 + w1*a1 + w2*a2 + w3*a3 + cb;
            u_l[t*641 + d] = silu_f(c);
            a0 = a1; a1 = a2; a2 = a3;
        }
    }
    __syncthreads();

    {
        int w = tid >> 6, l = tid & 63;
        #pragma unroll 1
        for (int pass = 0; pass < 3; ++pass) {
            float wreg[3][10];
            #pragma unroll
            for (int kk = 0; kk < 3; ++kk) {
                const float* xr = xW + (size_t)(w + 4*(3*pass + kk))*D_INNER + l;
                #pragma unroll
                for (int i = 0; i < 10; ++i) wreg[kk][i] = xr[64*i];
            }
            for (int t = 0; t < TT; ++t) {
                float ur[10];
                #pragma unroll
                for (int i = 0; i < 10; ++i) ur[i] = u_l[t*641 + l + 64*i];
                #pragma unroll
                for (int kk = 0; kk < 3; ++kk) {
                    float p = 0.f;
                    #pragma unroll
                    for (int i = 0; i < 10; ++i) p = fmaf(wreg[kk][i], ur[i], p);
                    #pragma unroll
                    for (int o = 32; o; o >>= 1) p += __shfl_xor(p, o);
                    if (l == t) xd_l[t*36 + w + 4*(3*pass + kk)] = p;
                }
            }
        }
        if (t_last < t0 + TT) {
            int tl = t_last - t0;
            float ur[10];
            #pragma unroll
            for (int i = 0; i < 10; ++i) ur[i] = u_l[tl*641 + l + 64*i];
            #pragma unroll
            for (int k = 0; k < 4; ++k) {
                const float* xr = xW + (size_t)(36 + w + 4*k)*D_INNER + l;
                float p = 0.f;
                #pragma unroll
                for (int i = 0; i < 10; ++i) p = fmaf(xr[64*i], ur[i], p);
                #pragma unroll
                for (int o = 32; o; o >>= 1) p += __shfl_xor(p, o);
                if (l == 0) ws[OFF_CLAST + b*16 + w + 4*k] = p;
            }
        }
    }
    __syncthreads();

    {
        int tmax = min(TT-1, t_last - t0);
        int cnt = (tmax + 1) * 36;
        float* dst = ws + OFF_XD + ((size_t)b*L_ + t0)*36;
        for (int o = tid; o < cnt; o += 256) dst[o] = xd_l[o];
    }
}

// ---------- K3: chunk-parallel fused scan (reg-cached dtW, exp2, b128 LDS) ----------
// grid (40, B, NCHUNK), block 256.
// Production threads: dd = tid&15 (one d), tg = tid>>4 (4 t each).
// Recurrence threads: dl = tid>>4 (d), s = tid&15.
__global__ __launch_bounds__(256) void k_scanc(
    const int* __restrict__ idx, const int* __restrict__ tissue_id,
    const int* __restrict__ seq_lengths,
    const float* __restrict__ conv_w, const float* __restrict__ conv_b,
    const float* __restrict__ dtW, const float* __restrict__ dtb,
    const float* __restrict__ A_log, float* __restrict__ ws)
{
    __shared__ float xd_t[ST*36];          // [t][36]
    __shared__ float dl_t[16*72];          // [d][t] stride 72 (b128-aligned)
    __shared__ float du_t[16*72];
    __shared__ int   idx_t[ST+3];

    int b = blockIdx.y, dg = blockIdx.x, c = blockIdx.z;
    int t_last = seq_lengths[b] - 1;
    int t_begin = c * CHLEN;
    if (t_begin > t_last) return;
    int t_end = min(t_begin + CHLEN - 1, t_last);
    int tid = threadIdx.x;
    int dl = tid >> 4, s = tid & 15;
    int dd = tid & 15, tg = tid >> 4;
    int d_own = dg*16 + dd;
    int tis = tissue_id[b];
    const float* Mseq = ws + OFF_MSEQ;

    // per-thread parameter registers (production identity: d_own)
    float dtw_r[20];
    #pragma unroll
    for (int i = 0; i < 20; i += 4) {
        float4 w4 = *(const float4*)(dtW + d_own*20 + i);
        dtw_r[i] = w4.x; dtw_r[i+1] = w4.y; dtw_r[i+2] = w4.z; dtw_r[i+3] = w4.w;
    }
    float4 cw4 = *(const float4*)(conv_w + d_own*4);
    float  cb  = conv_b[d_own];
    float  dtb_v = dtb[d_own];
    float  mt  = ws[OFF_MTIS + (size_t)tis*1280 + d_own];
    // recurrence identity: (dl, s)
    float As = -__expf(A_log[(dg*16 + dl)*D_STATE + s]) * 1.44269504089f;

    float h = 0.0f;     // chunk-local S
    float sd = 0.0f;    // sum of delta over chunk (per d of recurrence identity)
    for (int t0 = t_begin; t0 <= t_end; t0 += ST) {
        int nt = min(ST, t_end - t0 + 1);
        if (tid < ST+3) {
            int t = t0 - 3 + tid;
            idx_t[tid] = (t >= 0 && t < L_) ? idx[b*L_ + t] : 0;
        }
        {   // stage xd tile as float4
            const float4* src = (const float4*)(ws + OFF_XD + ((size_t)b*L_ + t0)*36);
            float4* dst = (float4*)xd_t;
            int cnt4 = nt * 9;
            for (int o = tid; o < cnt4; o += 256) dst[o] = src[o];
        }
        __syncthreads();

        // production: thread owns (d_own, t = tg*4 .. tg*4+3)
        {
            int ttb = tg * 4;
            if (ttb < nt) {
                float xz[7];
                #pragma unroll
                for (int k = 0; k < 7; ++k) {
                    int row = idx_t[ttb + k];
                    xz[k] = row ? (Mseq[(size_t)row*1280 + d_own] + mt) : 0.0f;
                }
                float dl4[4], du4[4];
                bool full = (ttb + 3 < nt);
                #pragma unroll
                for (int j = 0; j < 4; ++j) {
                    int tt = ttb + j;
                    if (full || tt < nt) {
                        float cc = cb;
                        cc = fmaf(cw4.x, xz[j+0], cc);
                        cc = fmaf(cw4.y, xz[j+1], cc);
                        cc = fmaf(cw4.z, xz[j+2], cc);
                        cc = fmaf(cw4.w, xz[j+3], cc);
                        float u = silu_f(cc);
                        const float* xr = xd_t + tt*36;
                        float x = dtb_v;
                        #pragma unroll
                        for (int r = 0; r < 20; r += 4) {
                            float4 x4 = *(const float4*)(xr + r);
                            x = fmaf(x4.x, dtw_r[r+0], x);
                            x = fmaf(x4.y, dtw_r[r+1], x);
                            x = fmaf(x4.z, dtw_r[r+2], x);
                            x = fmaf(x4.w, dtw_r[r+3], x);
                        }
                        // softplus: max(x,0) + log(1+exp(-|x|))
                        float e = __expf(-fabsf(x));
                        float sp = fmaxf(x, 0.0f) + __logf(1.0f + e);
                        dl4[j] = sp;
                        du4[j] = sp * u;
                    } else { dl4[j] = 0.f; du4[j] = 0.f; }
                }
                if (full) {
                    *(float4*)(dl_t + dd*72 + ttb) = make_float4(dl4[0], dl4[1], dl4[2], dl4[3]);
                    *(float4*)(du_t + dd*72 + ttb) = make_float4(du4[0], du4[1], du4[2], du4[3]);
                } else {
                    for (int j = 0; j < 4 && ttb + j < nt; ++j) {
                        dl_t[dd*72 + ttb + j] = dl4[j];
                        du_t[dd*72 + ttb + j] = du4[j];
                    }
                }
            }
        }
        __syncthreads();

        // recurrence: thread (dl, s)
        {
            int q4 = nt >> 2;
            for (int q = 0; q < q4; ++q) {
                float4 d4 = *(const float4*)(dl_t + dl*72 + 4*q);
                float4 u4 = *(const float4*)(du_t + dl*72 + 4*q);
                float b0 = xd_t[(4*q+0)*36 + 20 + s];
                float b1 = xd_t[(4*q+1)*36 + 20 + s];
                float b2 = xd_t[(4*q+2)*36 + 20 + s];
                float b3 = xd_t[(4*q+3)*36 + 20 + s];
                h = fmaf(exp2f(d4.x*As), h, u4.x*b0);
                h = fmaf(exp2f(d4.y*As), h, u4.y*b1);
                h = fmaf(exp2f(d4.z*As), h, u4.z*b2);
                h = fmaf(exp2f(d4.w*As), h, u4.w*b3);
                sd += (d4.x + d4.y) + (d4.z + d4.w);
            }
            for (int tt = q4*4; tt < nt; ++tt) {
                float dlt = dl_t[dl*72 + tt];
                h = fmaf(exp2f(dlt * As), h, du_t[dl*72 + tt] * xd_t[tt*36 + 20 + s]);
                sd += dlt;
            }
        }
        __syncthreads();
    }
    float P = exp2f(As * sd);
    size_t base = (((size_t)b*NCHUNK + c)*40 + dg)*256 + tid;
    ws[OFF_PC + base] = P;
    ws[OFF_SC + base] = h;
}

// ---------- K5: combine chunks + skip + gate + out_proj + MLP head (per batch) ----------
__global__ __launch_bounds__(320) void k_final(
    const int* __restrict__ idx, const int* __restrict__ tissue_id,
    const int* __restrict__ seq_lengths,
    const float* __restrict__ conv_w, const float* __restrict__ conv_b,
    const float* __restrict__ Dskip, const float* __restrict__ outW,
    const float* __restrict__ p1W, const float* __restrict__ p1b,
    const float* __restrict__ p2W, const float* __restrict__ p2b,
    const float* __restrict__ ws, float* __restrict__ out)
{
    __shared__ float y_l[D_INNER];
    __shared__ float o_l[D_MODEL];
    __shared__ float h1_l[H_OUT];
    __shared__ float cl_l[16];
    int b = blockIdx.x, tid = threadIdx.x;
    int t_last = seq_lengths[b] - 1;
    int ncv = t_last / CHLEN + 1;
    int tis = tissue_id[b];
    const float* Mseq = ws + OFF_MSEQ;
    const float* Mtis = ws + OFF_MTIS;
    if (tid < 16) cl_l[tid] = ws[OFF_CLAST + b*16 + tid];
    __syncthreads();

    int rows[4];
    #pragma unroll
    for (int k = 0; k < 4; ++k) {
        int t = t_last - 3 + k;
        rows[k] = (t >= 0) ? idx[b*L_ + t] : 0;
    }
    for (int d = tid; d < D_INNER; d += 320) {
        // chunk combine for this d
        int dgg = d >> 4, dll = d & 15;
        float hs[16];
        #pragma unroll
        for (int s = 0; s < 16; ++s) hs[s] = 0.0f;
        for (int c = 0; c < ncv; ++c) {
            const float* pc = ws + OFF_PC + (((size_t)b*NCHUNK + c)*40 + dgg)*256 + dll*16;
            const float* sc = ws + OFF_SC + (((size_t)b*NCHUNK + c)*40 + dgg)*256 + dll*16;
            #pragma unroll
            for (int s4 = 0; s4 < 4; ++s4) {
                float4 p = *(const float4*)(pc + 4*s4);
                float4 sv = *(const float4*)(sc + 4*s4);
                hs[4*s4+0] = fmaf(p.x, hs[4*s4+0], sv.x);
                hs[4*s4+1] = fmaf(p.y, hs[4*s4+1], sv.y);
                hs[4*s4+2] = fmaf(p.z, hs[4*s4+2], sv.z);
                hs[4*s4+3] = fmaf(p.w, hs[4*s4+3], sv.w);
            }
        }
        float ys = 0.0f;
        #pragma unroll
        for (int s = 0; s < 16; ++s) ys = fmaf(hs[s], cl_l[s], ys);

        float conv = conv_b[d];
        const float* cw = conv_w + d*4;
        #pragma unroll
        for (int k = 0; k < 4; ++k) {
            int row = rows[k];
            float xzv = row ? (Mseq[(size_t)row*1280 + d] + Mtis[(size_t)tis*1280 + d]) : 0.0f;
            conv += cw[k] * xzv;
        }
        float u = silu_f(conv);
        int rowL = rows[3];
        float z = rowL ? (Mseq[(size_t)rowL*1280 + 640 + d] + Mtis[(size_t)tis*1280 + 640 + d]) : 0.0f;
        y_l[d] = (ys + u * Dskip[d]) * silu_f(z);
    }
    __syncthreads();
    if (tid < D_MODEL) {
        const float* w = outW + tid*D_INNER;
        float acc = 0.f;
        #pragma unroll 4
        for (int k = 0; k < D_INNER; k += 4) {
            float4 w4 = *(const float4*)(w + k);
            acc += y_l[k]*w4.x + y_l[k+1]*w4.y + y_l[k+2]*w4.z + y_l[k+3]*w4.w;
        }
        o_l[tid] = acc;
    }
    __syncthreads();
    if (tid < H_OUT) {
        const float* w = p1W + tid*D_MODEL;
        float acc = p1b[tid];
        #pragma unroll 4
        for (int k = 0; k < D_MODEL; k += 4) {
            float4 w4 = *(const float4*)(w + k);
            acc += o_l[k]*w4.x + o_l[k+1]*w4.y + o_l[k+2]*w4.z + o_l[k+3]*w4.w;
        }
        h1_l[tid] = fmaxf(acc, 0.0f);
    }
    __syncthreads();
    if (tid == 0) {
        float acc = p2b[0];
        for (int k = 0; k < H_OUT; ++k) acc += h1_l[k]*p2W[k];
        out[b] = acc;
    }
}

extern "C" void kernel_launch(void* const* d_in, const int* in_sizes, int n_in,
                              void* d_out, int out_size, void* d_ws, size_t ws_size,
                              hipStream_t stream)
{
    const int*   idx   = (const int*)d_in[0];
    const int*   tis   = (const int*)d_in[1];
    const int*   slen  = (const int*)d_in[2];
    const float* seqW  = (const float*)d_in[3];
    const float* tisW  = (const float*)d_in[4];
    const float* inW   = (const float*)d_in[5];
    const float* convw = (const float*)d_in[6];
    const float* convb = (const float*)d_in[7];
    const float* xW    = (const float*)d_in[8];
    const float* dtW   = (const float*)d_in[9];
    const float* dtb   = (const float*)d_in[10];
    const float* Alog  = (const float*)d_in[11];
    const float* Dsk   = (const float*)d_in[12];
    const float* outW  = (const float*)d_in[13];
    const float* p1W   = (const float*)d_in[14];
    const float* p1b   = (const float*)d_in[15];
    const float* p2W   = (const float*)d_in[16];
    const float* p2b   = (const float*)d_in[17];
    float* ws  = (float*)d_ws;
    float* out = (float*)d_out;

    hipLaunchKernelGGL(k_mbuild, dim3(VOCAB + N_TIS, 5), dim3(256), 0, stream, seqW, tisW, inW, ws);
    hipLaunchKernelGGL(k_xdbl,   dim3(L_/TT, B_),        dim3(256), 0, stream,
                       idx, tis, slen, convw, convb, xW, ws);
    hipLaunchKernelGGL(k_scanc,  dim3(D_INNER/16, B_, NCHUNK), dim3(256), 0, stream,
                       idx, tis, slen, convw, convb, dtW, dtb, Alog, ws);
    hipLaunchKernelGGL(k_final,  dim3(B_),               dim3(320), 0, stream,
                       idx, tis, slen, convw, convb, Dsk, outW, p1W, p1b, p2W, p2b, ws, out);
}

// Round 8
// 276.102 us; speedup vs baseline: 1.8626x; 1.0699x over previous
//
#include <hip/hip_runtime.h>
#include <hip/hip_bf16.h>
#include <math.h>

#define B_      16
#define L_      2048
#define D_MODEL 320
#define D_INNER 640
#define D_STATE 16
#define DT_RANK 20
#define H_OUT   128
#define VOCAB   65
#define N_TIS   30
#define TT      8    // t-tile in xdbl producer
#define ST      64   // t-tile in fused scan
#define NCHUNK  16   // scan chunks (128 t each)
#define CHLEN   (L_/NCHUNK)

// workspace layout (floats)
static constexpr size_t OFF_MSEQ  = 0;                          // 65*1280
static constexpr size_t OFF_MTIS  = OFF_MSEQ + VOCAB*1280;      // 30*1280
static constexpr size_t OFF_YSCAN = OFF_MTIS + N_TIS*1280;      // 16*640 (unused)
static constexpr size_t OFF_CLAST = OFF_YSCAN + B_*D_INNER;     // 16*16
static constexpr size_t OFF_XD    = OFF_CLAST + B_*16;          // B*L*36 (rows 0..19 dt, 20..35 B)
static constexpr size_t OFF_PC    = OFF_XD + (size_t)B_*L_*36;  // B*NCHUNK*40*256
static constexpr size_t OFF_SC    = OFF_PC + (size_t)B_*NCHUNK*40*256;

__device__ __forceinline__ float silu_f(float x) { return x / (1.0f + __expf(-x)); }

// ---------- A0+A1 fused: renorm embedding row (max_norm=2) then M-row = row @ inW-slice^T ----------
__global__ __launch_bounds__(256) void k_mbuild(
    const float* __restrict__ seqW, const float* __restrict__ tisW,
    const float* __restrict__ inW, float* __restrict__ ws)
{
    __shared__ float a_l[256];
    __shared__ float red[4];
    int v = blockIdx.x, tid = threadIdx.x;
    int K, wofs; const float* src; float* dstM;
    if (v < VOCAB) { K = 256; wofs = 0;   src = seqW + (size_t)v*256;        dstM = ws + OFF_MSEQ + (size_t)v*1280; }
    else           { K = 64;  wofs = 256; src = tisW + (size_t)(v-VOCAB)*64; dstM = ws + OFF_MTIS + (size_t)(v-VOCAB)*1280; }
    float x = (tid < K) ? src[tid] : 0.0f;
    float ss = x * x;
    #pragma unroll
    for (int o = 32; o; o >>= 1) ss += __shfl_xor(ss, o);
    if ((tid & 63) == 0) red[tid >> 6] = ss;
    __syncthreads();
    float tot = red[0] + red[1] + red[2] + red[3];
    float scale = fminf(1.0f, 2.0f / fmaxf(sqrtf(tot), 1e-12f));
    if (tid < K) a_l[tid] = x * scale;
    __syncthreads();

    int j = blockIdx.y * 256 + tid;
    const float* w = inW + (size_t)j*320 + wofs;
    float ac0 = 0.f, ac1 = 0.f, ac2 = 0.f, ac3 = 0.f;
    #pragma unroll 4
    for (int k = 0; k < K; k += 4) {
        float4 w4 = *(const float4*)(w + k);
        ac0 += a_l[k+0]*w4.x; ac1 += a_l[k+1]*w4.y;
        ac2 += a_l[k+2]*w4.z; ac3 += a_l[k+3]*w4.w;
    }
    dstM[j] = (ac0 + ac1) + (ac2 + ac3);
}

// ---------- K2: conv+silu -> x_proj rows 0..35 -> xd[b][t][36]; C rows only at t_last ----------
// phase 2: single pass, wreg[9][10] (all 9 rows per wave), 9-way-ILP dot+butterfly.
__global__ __launch_bounds__(256) void k_xdbl(
    const int* __restrict__ idx, const int* __restrict__ tissue_id,
    const int* __restrict__ seq_lengths,
    const float* __restrict__ conv_w, const float* __restrict__ conv_b,
    const float* __restrict__ xW, float* __restrict__ ws)
{
    __shared__ float u_l[TT*641];
    __shared__ float xd_l[TT*36];
    __shared__ int   idx_l[TT+3];
    int b = blockIdx.y;
    int t0 = blockIdx.x * TT;
    int t_last = seq_lengths[b] - 1;
    if (t0 > t_last) return;
    int tid = threadIdx.x;
    const float* Mseq = ws + OFF_MSEQ;
    const float* Mtis = ws + OFF_MTIS;
    int tis = tissue_id[b];
    if (tid < TT+3) {
        int t = t0 - 3 + tid;
        idx_l[tid] = (t >= 0) ? idx[b*L_ + t] : 0;
    }
    __syncthreads();

    // phase 1: u = silu(causal depthwise conv4 of xz[:, :640])
    for (int d = tid; d < D_INNER; d += 256) {
        float w0 = conv_w[d*4+0], w1 = conv_w[d*4+1], w2 = conv_w[d*4+2], w3 = conv_w[d*4+3];
        float cb = conv_b[d];
        float mt = Mtis[(size_t)tis*1280 + d];
        auto XZ = [&](int k) -> float {
            int row = idx_l[k];
            return row ? (Mseq[(size_t)row*1280 + d] + mt) : 0.0f;
        };
        float a0 = XZ(0), a1 = XZ(1), a2 = XZ(2);
        for (int t = 0; t < TT; ++t) {
            float a3 = XZ(t+3);
            float c = w0*a0 + w1*a1 + w2*a2 + w3*a3 + cb;
            u_l[t*641 + d] = silu_f(c);
            a0 = a1; a1 = a2; a2 = a3;
        }
    }
    __syncthreads();

    // phase 2: wave w owns rows r = w + 4k, k<9. All 9 rows' weights in regs.
    {
        int w = tid >> 6, l = tid & 63;
        float wreg[9][10];
        #pragma unroll
        for (int kk = 0; kk < 9; ++kk) {
            const float* xr = xW + (size_t)(w + 4*kk)*D_INNER + l;
            #pragma unroll
            for (int i = 0; i < 10; ++i) wreg[kk][i] = xr[64*i];
        }
        for (int t = 0; t < TT; ++t) {
            float p[9];
            #pragma unroll
            for (int kk = 0; kk < 9; ++kk) p[kk] = 0.f;
            #pragma unroll
            for (int i = 0; i < 10; ++i) {
                float ui = u_l[t*641 + l + 64*i];
                #pragma unroll
                for (int kk = 0; kk < 9; ++kk) p[kk] = fmaf(wreg[kk][i], ui, p[kk]);
            }
            #pragma unroll
            for (int o = 32; o; o >>= 1) {
                #pragma unroll
                for (int kk = 0; kk < 9; ++kk) p[kk] += __shfl_xor(p[kk], o);
            }
            if (l == t) {
                #pragma unroll
                for (int kk = 0; kk < 9; ++kk) xd_l[t*36 + w + 4*kk] = p[kk];
            }
        }
        // C rows (xW rows 36..51): only t_last is consumed
        if (t_last < t0 + TT) {
            int tl = t_last - t0;
            float pc[4];
            #pragma unroll
            for (int k = 0; k < 4; ++k) pc[k] = 0.f;
            #pragma unroll
            for (int i = 0; i < 10; ++i) {
                float ui = u_l[tl*641 + l + 64*i];
                #pragma unroll
                for (int k = 0; k < 4; ++k)
                    pc[k] = fmaf(xW[(size_t)(36 + w + 4*k)*D_INNER + l + 64*i], ui, pc[k]);
            }
            #pragma unroll
            for (int o = 32; o; o >>= 1) {
                #pragma unroll
                for (int k = 0; k < 4; ++k) pc[k] += __shfl_xor(pc[k], o);
            }
            if (l == 0) {
                #pragma unroll
                for (int k = 0; k < 4; ++k) ws[OFF_CLAST + b*16 + w + 4*k] = pc[k];
            }
        }
    }
    __syncthreads();

    {
        int tmax = min(TT-1, t_last - t0);
        int cnt = (tmax + 1) * 36;
        float* dst = ws + OFF_XD + ((size_t)b*L_ + t0)*36;
        for (int o = tid; o < cnt; o += 256) dst[o] = xd_l[o];
    }
}

// ---------- K3: chunk-parallel fused scan (reg-cached dtW, exp2, b128 LDS) ----------
__global__ __launch_bounds__(256) void k_scanc(
    const int* __restrict__ idx, const int* __restrict__ tissue_id,
    const int* __restrict__ seq_lengths,
    const float* __restrict__ conv_w, const float* __restrict__ conv_b,
    const float* __restrict__ dtW, const float* __restrict__ dtb,
    const float* __restrict__ A_log, float* __restrict__ ws)
{
    __shared__ float xd_t[ST*36];          // [t][36]
    __shared__ float dl_t[16*72];          // [d][t] stride 72 (b128-aligned)
    __shared__ float du_t[16*72];
    __shared__ int   idx_t[ST+3];

    int b = blockIdx.y, dg = blockIdx.x, c = blockIdx.z;
    int t_last = seq_lengths[b] - 1;
    int t_begin = c * CHLEN;
    if (t_begin > t_last) return;
    int t_end = min(t_begin + CHLEN - 1, t_last);
    int tid = threadIdx.x;
    int dl = tid >> 4, s = tid & 15;
    int dd = tid & 15, tg = tid >> 4;
    int d_own = dg*16 + dd;
    int tis = tissue_id[b];
    const float* Mseq = ws + OFF_MSEQ;

    float dtw_r[20];
    #pragma unroll
    for (int i = 0; i < 20; i += 4) {
        float4 w4 = *(const float4*)(dtW + d_own*20 + i);
        dtw_r[i] = w4.x; dtw_r[i+1] = w4.y; dtw_r[i+2] = w4.z; dtw_r[i+3] = w4.w;
    }
    float4 cw4 = *(const float4*)(conv_w + d_own*4);
    float  cb  = conv_b[d_own];
    float  dtb_v = dtb[d_own];
    float  mt  = ws[OFF_MTIS + (size_t)tis*1280 + d_own];
    float As = -__expf(A_log[(dg*16 + dl)*D_STATE + s]) * 1.44269504089f;

    float h = 0.0f;
    float sd = 0.0f;
    for (int t0 = t_begin; t0 <= t_end; t0 += ST) {
        int nt = min(ST, t_end - t0 + 1);
        if (tid < ST+3) {
            int t = t0 - 3 + tid;
            idx_t[tid] = (t >= 0 && t < L_) ? idx[b*L_ + t] : 0;
        }
        {
            const float4* src = (const float4*)(ws + OFF_XD + ((size_t)b*L_ + t0)*36);
            float4* dst = (float4*)xd_t;
            int cnt4 = nt * 9;
            for (int o = tid; o < cnt4; o += 256) dst[o] = src[o];
        }
        __syncthreads();

        {
            int ttb = tg * 4;
            if (ttb < nt) {
                float xz[7];
                #pragma unroll
                for (int k = 0; k < 7; ++k) {
                    int row = idx_t[ttb + k];
                    xz[k] = row ? (Mseq[(size_t)row*1280 + d_own] + mt) : 0.0f;
                }
                float dl4[4], du4[4];
                bool full = (ttb + 3 < nt);
                #pragma unroll
                for (int j = 0; j < 4; ++j) {
                    int tt = ttb + j;
                    if (full || tt < nt) {
                        float cc = cb;
                        cc = fmaf(cw4.x, xz[j+0], cc);
                        cc = fmaf(cw4.y, xz[j+1], cc);
                        cc = fmaf(cw4.z, xz[j+2], cc);
                        cc = fmaf(cw4.w, xz[j+3], cc);
                        float u = silu_f(cc);
                        const float* xr = xd_t + tt*36;
                        float x = dtb_v;
                        #pragma unroll
                        for (int r = 0; r < 20; r += 4) {
                            float4 x4 = *(const float4*)(xr + r);
                            x = fmaf(x4.x, dtw_r[r+0], x);
                            x = fmaf(x4.y, dtw_r[r+1], x);
                            x = fmaf(x4.z, dtw_r[r+2], x);
                            x = fmaf(x4.w, dtw_r[r+3], x);
                        }
                        float e = __expf(-fabsf(x));
                        float sp = fmaxf(x, 0.0f) + __logf(1.0f + e);
                        dl4[j] = sp;
                        du4[j] = sp * u;
                    } else { dl4[j] = 0.f; du4[j] = 0.f; }
                }
                if (full) {
                    *(float4*)(dl_t + dd*72 + ttb) = make_float4(dl4[0], dl4[1], dl4[2], dl4[3]);
                    *(float4*)(du_t + dd*72 + ttb) = make_float4(du4[0], du4[1], du4[2], du4[3]);
                } else {
                    for (int j = 0; j < 4 && ttb + j < nt; ++j) {
                        dl_t[dd*72 + ttb + j] = dl4[j];
                        du_t[dd*72 + ttb + j] = du4[j];
                    }
                }
            }
        }
        __syncthreads();

        {
            int q4 = nt >> 2;
            for (int q = 0; q < q4; ++q) {
                float4 d4 = *(const float4*)(dl_t + dl*72 + 4*q);
                float4 u4 = *(const float4*)(du_t + dl*72 + 4*q);
                float b0 = xd_t[(4*q+0)*36 + 20 + s];
                float b1 = xd_t[(4*q+1)*36 + 20 + s];
                float b2 = xd_t[(4*q+2)*36 + 20 + s];
                float b3 = xd_t[(4*q+3)*36 + 20 + s];
                h = fmaf(exp2f(d4.x*As), h, u4.x*b0);
                h = fmaf(exp2f(d4.y*As), h, u4.y*b1);
                h = fmaf(exp2f(d4.z*As), h, u4.z*b2);
                h = fmaf(exp2f(d4.w*As), h, u4.w*b3);
                sd += (d4.x + d4.y) + (d4.z + d4.w);
            }
            for (int tt = q4*4; tt < nt; ++tt) {
                float dlt = dl_t[dl*72 + tt];
                h = fmaf(exp2f(dlt * As), h, du_t[dl*72 + tt] * xd_t[tt*36 + 20 + s]);
                sd += dlt;
            }
        }
        __syncthreads();
    }
    float P = exp2f(As * sd);
    size_t base = (((size_t)b*NCHUNK + c)*40 + dg)*256 + tid;
    ws[OFF_PC + base] = P;
    ws[OFF_SC + base] = h;
}

// ---------- K5: combine chunks + skip + gate + out_proj + MLP head (per batch) ----------
__global__ __launch_bounds__(320) void k_final(
    const int* __restrict__ idx, const int* __restrict__ tissue_id,
    const int* __restrict__ seq_lengths,
    const float* __restrict__ conv_w, const float* __restrict__ conv_b,
    const float* __restrict__ Dskip, const float* __restrict__ outW,
    const float* __restrict__ p1W, const float* __restrict__ p1b,
    const float* __restrict__ p2W, const float* __restrict__ p2b,
    const float* __restrict__ ws, float* __restrict__ out)
{
    __shared__ float y_l[D_INNER];
    __shared__ float o_l[D_MODEL];
    __shared__ float h1_l[H_OUT];
    __shared__ float cl_l[16];
    int b = blockIdx.x, tid = threadIdx.x;
    int t_last = seq_lengths[b] - 1;
    int ncv = t_last / CHLEN + 1;
    int tis = tissue_id[b];
    const float* Mseq = ws + OFF_MSEQ;
    const float* Mtis = ws + OFF_MTIS;
    if (tid < 16) cl_l[tid] = ws[OFF_CLAST + b*16 + tid];
    __syncthreads();

    int rows[4];
    #pragma unroll
    for (int k = 0; k < 4; ++k) {
        int t = t_last - 3 + k;
        rows[k] = (t >= 0) ? idx[b*L_ + t] : 0;
    }
    for (int d = tid; d < D_INNER; d += 320) {
        int dgg = d >> 4, dll = d & 15;
        float hs[16];
        #pragma unroll
        for (int s = 0; s < 16; ++s) hs[s] = 0.0f;
        for (int c = 0; c < ncv; ++c) {
            const float* pc = ws + OFF_PC + (((size_t)b*NCHUNK + c)*40 + dgg)*256 + dll*16;
            const float* sc = ws + OFF_SC + (((size_t)b*NCHUNK + c)*40 + dgg)*256 + dll*16;
            #pragma unroll
            for (int s4 = 0; s4 < 4; ++s4) {
                float4 p = *(const float4*)(pc + 4*s4);
                float4 sv = *(const float4*)(sc + 4*s4);
                hs[4*s4+0] = fmaf(p.x, hs[4*s4+0], sv.x);
                hs[4*s4+1] = fmaf(p.y, hs[4*s4+1], sv.y);
                hs[4*s4+2] = fmaf(p.z, hs[4*s4+2], sv.z);
                hs[4*s4+3] = fmaf(p.w, hs[4*s4+3], sv.w);
            }
        }
        float ys = 0.0f;
        #pragma unroll
        for (int s = 0; s < 16; ++s) ys = fmaf(hs[s], cl_l[s], ys);

        float conv = conv_b[d];
        const float* cw = conv_w + d*4;
        #pragma unroll
        for (int k = 0; k < 4; ++k) {
            int row = rows[k];
            float xzv = row ? (Mseq[(size_t)row*1280 + d] + Mtis[(size_t)tis*1280 + d]) : 0.0f;
            conv += cw[k] * xzv;
        }
        float u = silu_f(conv);
        int rowL = rows[3];
        float z = rowL ? (Mseq[(size_t)rowL*1280 + 640 + d] + Mtis[(size_t)tis*1280 + 640 + d]) : 0.0f;
        y_l[d] = (ys + u * Dskip[d]) * silu_f(z);
    }
    __syncthreads();
    if (tid < D_MODEL) {
        const float* w = outW + tid*D_INNER;
        float acc = 0.f;
        #pragma unroll 4
        for (int k = 0; k < D_INNER; k += 4) {
            float4 w4 = *(const float4*)(w + k);
            acc += y_l[k]*w4.x + y_l[k+1]*w4.y + y_l[k+2]*w4.z + y_l[k+3]*w4.w;
        }
        o_l[tid] = acc;
    }
    __syncthreads();
    if (tid < H_OUT) {
        const float* w = p1W + tid*D_MODEL;
        float acc = p1b[tid];
        #pragma unroll 4
        for (int k = 0; k < D_MODEL; k += 4) {
            float4 w4 = *(const float4*)(w + k);
            acc += o_l[k]*w4.x + o_l[k+1]*w4.y + o_l[k+2]*w4.z + o_l[k+3]*w4.w;
        }
        h1_l[tid] = fmaxf(acc, 0.0f);
    }
    __syncthreads();
    if (tid == 0) {
        float acc = p2b[0];
        for (int k = 0; k < H_OUT; ++k) acc += h1_l[k]*p2W[k];
        out[b] = acc;
    }
}

extern "C" void kernel_launch(void* const* d_in, const int* in_sizes, int n_in,
                              void* d_out, int out_size, void* d_ws, size_t ws_size,
                              hipStream_t stream)
{
    const int*   idx   = (const int*)d_in[0];
    const int*   tis   = (const int*)d_in[1];
    const int*   slen  = (const int*)d_in[2];
    const float* seqW  = (const float*)d_in[3];
    const float* tisW  = (const float*)d_in[4];
    const float* inW   = (const float*)d_in[5];
    const float* convw = (const float*)d_in[6];
    const float* convb = (const float*)d_in[7];
    const float* xW    = (const float*)d_in[8];
    const float* dtW   = (const float*)d_in[9];
    const float* dtb   = (const float*)d_in[10];
    const float* Alog  = (const float*)d_in[11];
    const float* Dsk   = (const float*)d_in[12];
    const float* outW  = (const float*)d_in[13];
    const float* p1W   = (const float*)d_in[14];
    const float* p1b   = (const float*)d_in[15];
    const float* p2W   = (const float*)d_in[16];
    const float* p2b   = (const float*)d_in[17];
    float* ws  = (float*)d_ws;
    float* out = (float*)d_out;

    hipLaunchKernelGGL(k_mbuild, dim3(VOCAB + N_TIS, 5), dim3(256), 0, stream, seqW, tisW, inW, ws);
    hipLaunchKernelGGL(k_xdbl,   dim3(L_/TT, B_),        dim3(256), 0, stream,
                       idx, tis, slen, convw, convb, xW, ws);
    hipLaunchKernelGGL(k_scanc,  dim3(D_INNER/16, B_, NCHUNK), dim3(256), 0, stream,
                       idx, tis, slen, convw, convb, dtW, dtb, Alog, ws);
    hipLaunchKernelGGL(k_final,  dim3(B_),               dim3(320), 0, stream,
                       idx, tis, slen, convw, convb, Dsk, outW, p1W, p1b, p2W, p2b, ws, out);
}

// Round 9
// 271.829 us; speedup vs baseline: 1.8919x; 1.0157x over previous
//
#include <hip/hip_runtime.h>
#include <hip/hip_bf16.h>
#include <math.h>

#define B_      16
#define L_      2048
#define D_MODEL 320
#define D_INNER 640
#define D_STATE 16
#define DT_RANK 20
#define H_OUT   128
#define VOCAB   65
#define N_TIS   30
#define TT      8    // t-tile in xdbl producer
#define ST      64   // t-tile in fused scan
#define NCHUNK  16   // scan chunks (128 t each)
#define CHLEN   (L_/NCHUNK)

// workspace layout (floats)
static constexpr size_t OFF_MSEQ  = 0;                          // 65*1280
static constexpr size_t OFF_MTIS  = OFF_MSEQ + VOCAB*1280;      // 30*1280
static constexpr size_t OFF_YSCAN = OFF_MTIS + N_TIS*1280;      // 16*640
static constexpr size_t OFF_CLAST = OFF_YSCAN + B_*D_INNER;     // 16*16
static constexpr size_t OFF_XD    = OFF_CLAST + B_*16;          // B*L*36 (rows 0..19 dt, 20..35 B)
static constexpr size_t OFF_PC    = OFF_XD + (size_t)B_*L_*36;  // B*NCHUNK*40*256
static constexpr size_t OFF_SC    = OFF_PC + (size_t)B_*NCHUNK*40*256;

__device__ __forceinline__ float silu_f(float x) { return x / (1.0f + __expf(-x)); }

// ---------- A0+A1 fused: renorm embedding row (max_norm=2) then M-row = row @ inW-slice^T ----------
__global__ __launch_bounds__(256) void k_mbuild(
    const float* __restrict__ seqW, const float* __restrict__ tisW,
    const float* __restrict__ inW, float* __restrict__ ws)
{
    __shared__ float a_l[256];
    __shared__ float red[4];
    int v = blockIdx.x, tid = threadIdx.x;
    int K, wofs; const float* src; float* dstM;
    if (v < VOCAB) { K = 256; wofs = 0;   src = seqW + (size_t)v*256;        dstM = ws + OFF_MSEQ + (size_t)v*1280; }
    else           { K = 64;  wofs = 256; src = tisW + (size_t)(v-VOCAB)*64; dstM = ws + OFF_MTIS + (size_t)(v-VOCAB)*1280; }
    float x = (tid < K) ? src[tid] : 0.0f;
    float ss = x * x;
    #pragma unroll
    for (int o = 32; o; o >>= 1) ss += __shfl_xor(ss, o);
    if ((tid & 63) == 0) red[tid >> 6] = ss;
    __syncthreads();
    float tot = red[0] + red[1] + red[2] + red[3];
    float scale = fminf(1.0f, 2.0f / fmaxf(sqrtf(tot), 1e-12f));
    if (tid < K) a_l[tid] = x * scale;
    __syncthreads();

    int j = blockIdx.y * 256 + tid;
    const float* w = inW + (size_t)j*320 + wofs;
    float ac0 = 0.f, ac1 = 0.f, ac2 = 0.f, ac3 = 0.f;
    #pragma unroll 4
    for (int k = 0; k < K; k += 4) {
        float4 w4 = *(const float4*)(w + k);
        ac0 += a_l[k+0]*w4.x; ac1 += a_l[k+1]*w4.y;
        ac2 += a_l[k+2]*w4.z; ac3 += a_l[k+3]*w4.w;
    }
    dstM[j] = (ac0 + ac1) + (ac2 + ac3);
}

// ---------- K2: conv+silu -> x_proj rows 0..35 -> xd[b][t][36]; C rows only at t_last ----------
__global__ __launch_bounds__(256) void k_xdbl(
    const int* __restrict__ idx, const int* __restrict__ tissue_id,
    const int* __restrict__ seq_lengths,
    const float* __restrict__ conv_w, const float* __restrict__ conv_b,
    const float* __restrict__ xW, float* __restrict__ ws)
{
    __shared__ float u_l[TT*641];
    __shared__ float xd_l[TT*36];
    __shared__ int   idx_l[TT+3];
    int b = blockIdx.y;
    int t0 = blockIdx.x * TT;
    int t_last = seq_lengths[b] - 1;
    if (t0 > t_last) return;
    int tid = threadIdx.x;
    const float* Mseq = ws + OFF_MSEQ;
    const float* Mtis = ws + OFF_MTIS;
    int tis = tissue_id[b];
    if (tid < TT+3) {
        int t = t0 - 3 + tid;
        idx_l[tid] = (t >= 0) ? idx[b*L_ + t] : 0;
    }
    __syncthreads();

    // phase 1: u = silu(causal depthwise conv4). Explicit prefetch of all 11 gathers
    // so the load latencies overlap instead of serializing through the rolling window.
    for (int d = tid; d < D_INNER; d += 256) {
        float w0 = conv_w[d*4+0], w1 = conv_w[d*4+1], w2 = conv_w[d*4+2], w3 = conv_w[d*4+3];
        float cb = conv_b[d];
        float mt = Mtis[(size_t)tis*1280 + d];
        float xzv[TT+3];
        #pragma unroll
        for (int k = 0; k < TT+3; ++k) {
            int row = idx_l[k];
            xzv[k] = row ? (Mseq[(size_t)row*1280 + d] + mt) : 0.0f;
        }
        #pragma unroll
        for (int t = 0; t < TT; ++t) {
            float c = cb;
            c = fmaf(w0, xzv[t+0], c);
            c = fmaf(w1, xzv[t+1], c);
            c = fmaf(w2, xzv[t+2], c);
            c = fmaf(w3, xzv[t+3], c);
            u_l[t*641 + d] = silu_f(c);
        }
    }
    __syncthreads();

    // phase 2: wave w owns rows r = w + 4k, k<9. All 9 rows' weights in regs, 9-way ILP.
    {
        int w = tid >> 6, l = tid & 63;
        float wreg[9][10];
        #pragma unroll
        for (int kk = 0; kk < 9; ++kk) {
            const float* xr = xW + (size_t)(w + 4*kk)*D_INNER + l;
            #pragma unroll
            for (int i = 0; i < 10; ++i) wreg[kk][i] = xr[64*i];
        }
        for (int t = 0; t < TT; ++t) {
            float p[9];
            #pragma unroll
            for (int kk = 0; kk < 9; ++kk) p[kk] = 0.f;
            #pragma unroll
            for (int i = 0; i < 10; ++i) {
                float ui = u_l[t*641 + l + 64*i];
                #pragma unroll
                for (int kk = 0; kk < 9; ++kk) p[kk] = fmaf(wreg[kk][i], ui, p[kk]);
            }
            #pragma unroll
            for (int o = 32; o; o >>= 1) {
                #pragma unroll
                for (int kk = 0; kk < 9; ++kk) p[kk] += __shfl_xor(p[kk], o);
            }
            if (l == t) {
                #pragma unroll
                for (int kk = 0; kk < 9; ++kk) xd_l[t*36 + w + 4*kk] = p[kk];
            }
        }
        // C rows (xW rows 36..51): only t_last is consumed
        if (t_last < t0 + TT) {
            int tl = t_last - t0;
            float pc[4];
            #pragma unroll
            for (int k = 0; k < 4; ++k) pc[k] = 0.f;
            #pragma unroll
            for (int i = 0; i < 10; ++i) {
                float ui = u_l[tl*641 + l + 64*i];
                #pragma unroll
                for (int k = 0; k < 4; ++k)
                    pc[k] = fmaf(xW[(size_t)(36 + w + 4*k)*D_INNER + l + 64*i], ui, pc[k]);
            }
            #pragma unroll
            for (int o = 32; o; o >>= 1) {
                #pragma unroll
                for (int k = 0; k < 4; ++k) pc[k] += __shfl_xor(pc[k], o);
            }
            if (l == 0) {
                #pragma unroll
                for (int k = 0; k < 4; ++k) ws[OFF_CLAST + b*16 + w + 4*k] = pc[k];
            }
        }
    }
    __syncthreads();

    {
        int tmax = min(TT-1, t_last - t0);
        int cnt = (tmax + 1) * 36;
        float* dst = ws + OFF_XD + ((size_t)b*L_ + t0)*36;
        for (int o = tid; o < cnt; o += 256) dst[o] = xd_l[o];
    }
}

// ---------- K3: chunk-parallel fused scan (reg-cached dtW, exp2, b128 LDS) ----------
__global__ __launch_bounds__(256) void k_scanc(
    const int* __restrict__ idx, const int* __restrict__ tissue_id,
    const int* __restrict__ seq_lengths,
    const float* __restrict__ conv_w, const float* __restrict__ conv_b,
    const float* __restrict__ dtW, const float* __restrict__ dtb,
    const float* __restrict__ A_log, float* __restrict__ ws)
{
    __shared__ float xd_t[ST*36];          // [t][36]
    __shared__ float dl_t[16*72];          // [d][t] stride 72 (b128-aligned)
    __shared__ float du_t[16*72];
    __shared__ int   idx_t[ST+3];

    int b = blockIdx.y, dg = blockIdx.x, c = blockIdx.z;
    int t_last = seq_lengths[b] - 1;
    int t_begin = c * CHLEN;
    if (t_begin > t_last) return;
    int t_end = min(t_begin + CHLEN - 1, t_last);
    int tid = threadIdx.x;
    int dl = tid >> 4, s = tid & 15;
    int dd = tid & 15, tg = tid >> 4;
    int d_own = dg*16 + dd;
    int tis = tissue_id[b];
    const float* Mseq = ws + OFF_MSEQ;

    float dtw_r[20];
    #pragma unroll
    for (int i = 0; i < 20; i += 4) {
        float4 w4 = *(const float4*)(dtW + d_own*20 + i);
        dtw_r[i] = w4.x; dtw_r[i+1] = w4.y; dtw_r[i+2] = w4.z; dtw_r[i+3] = w4.w;
    }
    float4 cw4 = *(const float4*)(conv_w + d_own*4);
    float  cb  = conv_b[d_own];
    float  dtb_v = dtb[d_own];
    float  mt  = ws[OFF_MTIS + (size_t)tis*1280 + d_own];
    float As = -__expf(A_log[(dg*16 + dl)*D_STATE + s]) * 1.44269504089f;

    float h = 0.0f;
    float sd = 0.0f;
    for (int t0 = t_begin; t0 <= t_end; t0 += ST) {
        int nt = min(ST, t_end - t0 + 1);
        if (tid < ST+3) {
            int t = t0 - 3 + tid;
            idx_t[tid] = (t >= 0 && t < L_) ? idx[b*L_ + t] : 0;
        }
        {
            const float4* src = (const float4*)(ws + OFF_XD + ((size_t)b*L_ + t0)*36);
            float4* dst = (float4*)xd_t;
            int cnt4 = nt * 9;
            for (int o = tid; o < cnt4; o += 256) dst[o] = src[o];
        }
        __syncthreads();

        {
            int ttb = tg * 4;
            if (ttb < nt) {
                float xz[7];
                #pragma unroll
                for (int k = 0; k < 7; ++k) {
                    int row = idx_t[ttb + k];
                    xz[k] = row ? (Mseq[(size_t)row*1280 + d_own] + mt) : 0.0f;
                }
                float dl4[4], du4[4];
                bool full = (ttb + 3 < nt);
                #pragma unroll
                for (int j = 0; j < 4; ++j) {
                    int tt = ttb + j;
                    if (full || tt < nt) {
                        float cc = cb;
                        cc = fmaf(cw4.x, xz[j+0], cc);
                        cc = fmaf(cw4.y, xz[j+1], cc);
                        cc = fmaf(cw4.z, xz[j+2], cc);
                        cc = fmaf(cw4.w, xz[j+3], cc);
                        float u = silu_f(cc);
                        const float* xr = xd_t + tt*36;
                        float x = dtb_v;
                        #pragma unroll
                        for (int r = 0; r < 20; r += 4) {
                            float4 x4 = *(const float4*)(xr + r);
                            x = fmaf(x4.x, dtw_r[r+0], x);
                            x = fmaf(x4.y, dtw_r[r+1], x);
                            x = fmaf(x4.z, dtw_r[r+2], x);
                            x = fmaf(x4.w, dtw_r[r+3], x);
                        }
                        float e = __expf(-fabsf(x));
                        float sp = fmaxf(x, 0.0f) + __logf(1.0f + e);
                        dl4[j] = sp;
                        du4[j] = sp * u;
                    } else { dl4[j] = 0.f; du4[j] = 0.f; }
                }
                if (full) {
                    *(float4*)(dl_t + dd*72 + ttb) = make_float4(dl4[0], dl4[1], dl4[2], dl4[3]);
                    *(float4*)(du_t + dd*72 + ttb) = make_float4(du4[0], du4[1], du4[2], du4[3]);
                } else {
                    for (int j = 0; j < 4 && ttb + j < nt; ++j) {
                        dl_t[dd*72 + ttb + j] = dl4[j];
                        du_t[dd*72 + ttb + j] = du4[j];
                    }
                }
            }
        }
        __syncthreads();

        {
            int q4 = nt >> 2;
            for (int q = 0; q < q4; ++q) {
                float4 d4 = *(const float4*)(dl_t + dl*72 + 4*q);
                float4 u4 = *(const float4*)(du_t + dl*72 + 4*q);
                float b0 = xd_t[(4*q+0)*36 + 20 + s];
                float b1 = xd_t[(4*q+1)*36 + 20 + s];
                float b2 = xd_t[(4*q+2)*36 + 20 + s];
                float b3 = xd_t[(4*q+3)*36 + 20 + s];
                h = fmaf(exp2f(d4.x*As), h, u4.x*b0);
                h = fmaf(exp2f(d4.y*As), h, u4.y*b1);
                h = fmaf(exp2f(d4.z*As), h, u4.z*b2);
                h = fmaf(exp2f(d4.w*As), h, u4.w*b3);
                sd += (d4.x + d4.y) + (d4.z + d4.w);
            }
            for (int tt = q4*4; tt < nt; ++tt) {
                float dlt = dl_t[dl*72 + tt];
                h = fmaf(exp2f(dlt * As), h, du_t[dl*72 + tt] * xd_t[tt*36 + 20 + s]);
                sd += dlt;
            }
        }
        __syncthreads();
    }
    float P = exp2f(As * sd);
    size_t base = (((size_t)b*NCHUNK + c)*40 + dg)*256 + tid;
    ws[OFF_PC + base] = P;
    ws[OFF_SC + base] = h;
}

// ---------- K3b: combine chunk transfers, apply C_last, reduce over s (coalesced, 640 blocks) ----------
__global__ __launch_bounds__(256) void k_comb(const int* __restrict__ seq_lengths,
                                              float* __restrict__ ws)
{
    int b = blockIdx.y, dg = blockIdx.x;
    int tid = threadIdx.x;
    int dl = tid >> 4, s = tid & 15;
    int t_last = seq_lengths[b] - 1;
    int ncv = t_last / CHLEN + 1;
    float h = 0.0f;
    for (int c = 0; c < ncv; ++c) {
        size_t base = (((size_t)b*NCHUNK + c)*40 + dg)*256 + tid;
        h = fmaf(ws[OFF_PC + base], h, ws[OFF_SC + base]);
    }
    float v = h * ws[OFF_CLAST + b*16 + s];
    v += __shfl_xor(v, 1); v += __shfl_xor(v, 2);
    v += __shfl_xor(v, 4); v += __shfl_xor(v, 8);
    if (s == 0) ws[OFF_YSCAN + (size_t)b*D_INNER + dg*16 + dl] = v;
}

// ---------- K5: per-batch epilogue: skip + gate + out_proj + MLP head ----------
__global__ __launch_bounds__(320) void k_final(
    const int* __restrict__ idx, const int* __restrict__ tissue_id,
    const int* __restrict__ seq_lengths,
    const float* __restrict__ conv_w, const float* __restrict__ conv_b,
    const float* __restrict__ Dskip, const float* __restrict__ outW,
    const float* __restrict__ p1W, const float* __restrict__ p1b,
    const float* __restrict__ p2W, const float* __restrict__ p2b,
    const float* __restrict__ ws, float* __restrict__ out)
{
    __shared__ float y_l[D_INNER];
    __shared__ float o_l[D_MODEL];
    __shared__ float h1_l[H_OUT];
    int b = blockIdx.x, tid = threadIdx.x;
    int t_last = seq_lengths[b] - 1;
    int tis = tissue_id[b];
    const float* Mseq = ws + OFF_MSEQ;
    const float* Mtis = ws + OFF_MTIS;
    int rows[4];
    #pragma unroll
    for (int k = 0; k < 4; ++k) {
        int t = t_last - 3 + k;
        rows[k] = (t >= 0) ? idx[b*L_ + t] : 0;
    }
    for (int d = tid; d < D_INNER; d += 320) {
        float conv = conv_b[d];
        const float* cw = conv_w + d*4;
        #pragma unroll
        for (int k = 0; k < 4; ++k) {
            int row = rows[k];
            float xzv = row ? (Mseq[(size_t)row*1280 + d] + Mtis[(size_t)tis*1280 + d]) : 0.0f;
            conv += cw[k] * xzv;
        }
        float u = silu_f(conv);
        int rowL = rows[3];
        float z = rowL ? (Mseq[(size_t)rowL*1280 + 640 + d] + Mtis[(size_t)tis*1280 + 640 + d]) : 0.0f;
        float ys = ws[OFF_YSCAN + (size_t)b*D_INNER + d];
        y_l[d] = (ys + u * Dskip[d]) * silu_f(z);
    }
    __syncthreads();
    if (tid < D_MODEL) {
        const float* w = outW + tid*D_INNER;
        float acc = 0.f;
        #pragma unroll 4
        for (int k = 0; k < D_INNER; k += 4) {
            float4 w4 = *(const float4*)(w + k);
            acc += y_l[k]*w4.x + y_l[k+1]*w4.y + y_l[k+2]*w4.z + y_l[k+3]*w4.w;
        }
        o_l[tid] = acc;
    }
    __syncthreads();
    if (tid < H_OUT) {
        const float* w = p1W + tid*D_MODEL;
        float acc = p1b[tid];
        #pragma unroll 4
        for (int k = 0; k < D_MODEL; k += 4) {
            float4 w4 = *(const float4*)(w + k);
            acc += o_l[k]*w4.x + o_l[k+1]*w4.y + o_l[k+2]*w4.z + o_l[k+3]*w4.w;
        }
        h1_l[tid] = fmaxf(acc, 0.0f);
    }
    __syncthreads();
    if (tid == 0) {
        float acc = p2b[0];
        for (int k = 0; k < H_OUT; ++k) acc += h1_l[k]*p2W[k];
        out[b] = acc;
    }
}

extern "C" void kernel_launch(void* const* d_in, const int* in_sizes, int n_in,
                              void* d_out, int out_size, void* d_ws, size_t ws_size,
                              hipStream_t stream)
{
    const int*   idx   = (const int*)d_in[0];
    const int*   tis   = (const int*)d_in[1];
    const int*   slen  = (const int*)d_in[2];
    const float* seqW  = (const float*)d_in[3];
    const float* tisW  = (const float*)d_in[4];
    const float* inW   = (const float*)d_in[5];
    const float* convw = (const float*)d_in[6];
    const float* convb = (const float*)d_in[7];
    const float* xW    = (const float*)d_in[8];
    const float* dtW   = (const float*)d_in[9];
    const float* dtb   = (const float*)d_in[10];
    const float* Alog  = (const float*)d_in[11];
    const float* Dsk   = (const float*)d_in[12];
    const float* outW  = (const float*)d_in[13];
    const float* p1W   = (const float*)d_in[14];
    const float* p1b   = (const float*)d_in[15];
    const float* p2W   = (const float*)d_in[16];
    const float* p2b   = (const float*)d_in[17];
    float* ws  = (float*)d_ws;
    float* out = (float*)d_out;

    hipLaunchKernelGGL(k_mbuild, dim3(VOCAB + N_TIS, 5), dim3(256), 0, stream, seqW, tisW, inW, ws);
    hipLaunchKernelGGL(k_xdbl,   dim3(L_/TT, B_),        dim3(256), 0, stream,
                       idx, tis, slen, convw, convb, xW, ws);
    hipLaunchKernelGGL(k_scanc,  dim3(D_INNER/16, B_, NCHUNK), dim3(256), 0, stream,
                       idx, tis, slen, convw, convb, dtW, dtb, Alog, ws);
    hipLaunchKernelGGL(k_comb,   dim3(D_INNER/16, B_),   dim3(256), 0, stream, slen, ws);
    hipLaunchKernelGGL(k_final,  dim3(B_),               dim3(320), 0, stream,
                       idx, tis, slen, convw, convb, Dsk, outW, p1W, p1b, p2W, p2b, ws, out);
}

// Round 10
// 269.906 us; speedup vs baseline: 1.9054x; 1.0071x over previous
//
#include <hip/hip_runtime.h>
#include <hip/hip_bf16.h>
#include <math.h>

#define B_      16
#define L_      2048
#define D_MODEL 320
#define D_INNER 640
#define D_STATE 16
#define DT_RANK 20
#define H_OUT   128
#define VOCAB   65
#define N_TIS   30
#define TT      8    // t-tile in xdbl producer
#define ST      64   // t-tile in fused scan
#define NCHUNK  16   // scan chunks (128 t each)
#define CHLEN   (L_/NCHUNK)

// workspace layout (floats)
static constexpr size_t OFF_MSEQ  = 0;                          // 65*1280
static constexpr size_t OFF_MTIS  = OFF_MSEQ + VOCAB*1280;      // 30*1280
static constexpr size_t OFF_YSCAN = OFF_MTIS + N_TIS*1280;      // 16*640
static constexpr size_t OFF_CLAST = OFF_YSCAN + B_*D_INNER;     // 16*16
static constexpr size_t OFF_XD    = OFF_CLAST + B_*16;          // B*L*36 (rows 0..19 dt, 20..35 B)
static constexpr size_t OFF_PC    = OFF_XD + (size_t)B_*L_*36;  // B*NCHUNK*40*256
static constexpr size_t OFF_SC    = OFF_PC + (size_t)B_*NCHUNK*40*256;

__device__ __forceinline__ float silu_f(float x) { return x / (1.0f + __expf(-x)); }

// ---------- A0+A1 fused: renorm embedding row (max_norm=2) then M-row = row @ inW-slice^T ----------
__global__ __launch_bounds__(256) void k_mbuild(
    const float* __restrict__ seqW, const float* __restrict__ tisW,
    const float* __restrict__ inW, float* __restrict__ ws)
{
    __shared__ float a_l[256];
    __shared__ float red[4];
    int v = blockIdx.x, tid = threadIdx.x;
    int K, wofs; const float* src; float* dstM;
    if (v < VOCAB) { K = 256; wofs = 0;   src = seqW + (size_t)v*256;        dstM = ws + OFF_MSEQ + (size_t)v*1280; }
    else           { K = 64;  wofs = 256; src = tisW + (size_t)(v-VOCAB)*64; dstM = ws + OFF_MTIS + (size_t)(v-VOCAB)*1280; }
    float x = (tid < K) ? src[tid] : 0.0f;
    float ss = x * x;
    #pragma unroll
    for (int o = 32; o; o >>= 1) ss += __shfl_xor(ss, o);
    if ((tid & 63) == 0) red[tid >> 6] = ss;
    __syncthreads();
    float tot = red[0] + red[1] + red[2] + red[3];
    float scale = fminf(1.0f, 2.0f / fmaxf(sqrtf(tot), 1e-12f));
    if (tid < K) a_l[tid] = x * scale;
    __syncthreads();

    int j = blockIdx.y * 256 + tid;
    const float* w = inW + (size_t)j*320 + wofs;
    float ac0 = 0.f, ac1 = 0.f, ac2 = 0.f, ac3 = 0.f;
    #pragma unroll 4
    for (int k = 0; k < K; k += 4) {
        float4 w4 = *(const float4*)(w + k);
        ac0 += a_l[k+0]*w4.x; ac1 += a_l[k+1]*w4.y;
        ac2 += a_l[k+2]*w4.z; ac3 += a_l[k+3]*w4.w;
    }
    dstM[j] = (ac0 + ac1) + (ac2 + ac3);
}

// ---------- K2: conv+silu -> x_proj rows 0..35 -> xd[b][t][36]; C rows only at t_last ----------
__global__ __launch_bounds__(256) void k_xdbl(
    const int* __restrict__ idx, const int* __restrict__ tissue_id,
    const int* __restrict__ seq_lengths,
    const float* __restrict__ conv_w, const float* __restrict__ conv_b,
    const float* __restrict__ xW, float* __restrict__ ws)
{
    __shared__ float u_l[TT*641];
    __shared__ float xd_l[TT*36];
    __shared__ int   idx_l[TT+3];
    int b = blockIdx.y;
    int t0 = blockIdx.x * TT;
    int t_last = seq_lengths[b] - 1;
    if (t0 > t_last) return;
    int tid = threadIdx.x;
    const float* Mseq = ws + OFF_MSEQ;
    const float* Mtis = ws + OFF_MTIS;
    int tis = tissue_id[b];
    if (tid < TT+3) {
        int t = t0 - 3 + tid;
        idx_l[tid] = (t >= 0) ? idx[b*L_ + t] : 0;
    }
    __syncthreads();

    for (int d = tid; d < D_INNER; d += 256) {
        float w0 = conv_w[d*4+0], w1 = conv_w[d*4+1], w2 = conv_w[d*4+2], w3 = conv_w[d*4+3];
        float cb = conv_b[d];
        float mt = Mtis[(size_t)tis*1280 + d];
        float xzv[TT+3];
        #pragma unroll
        for (int k = 0; k < TT+3; ++k) {
            int row = idx_l[k];
            xzv[k] = row ? (Mseq[(size_t)row*1280 + d] + mt) : 0.0f;
        }
        #pragma unroll
        for (int t = 0; t < TT; ++t) {
            float c = cb;
            c = fmaf(w0, xzv[t+0], c);
            c = fmaf(w1, xzv[t+1], c);
            c = fmaf(w2, xzv[t+2], c);
            c = fmaf(w3, xzv[t+3], c);
            u_l[t*641 + d] = silu_f(c);
        }
    }
    __syncthreads();

    {
        int w = tid >> 6, l = tid & 63;
        float wreg[9][10];
        #pragma unroll
        for (int kk = 0; kk < 9; ++kk) {
            const float* xr = xW + (size_t)(w + 4*kk)*D_INNER + l;
            #pragma unroll
            for (int i = 0; i < 10; ++i) wreg[kk][i] = xr[64*i];
        }
        for (int t = 0; t < TT; ++t) {
            float p[9];
            #pragma unroll
            for (int kk = 0; kk < 9; ++kk) p[kk] = 0.f;
            #pragma unroll
            for (int i = 0; i < 10; ++i) {
                float ui = u_l[t*641 + l + 64*i];
                #pragma unroll
                for (int kk = 0; kk < 9; ++kk) p[kk] = fmaf(wreg[kk][i], ui, p[kk]);
            }
            #pragma unroll
            for (int o = 32; o; o >>= 1) {
                #pragma unroll
                for (int kk = 0; kk < 9; ++kk) p[kk] += __shfl_xor(p[kk], o);
            }
            if (l == t) {
                #pragma unroll
                for (int kk = 0; kk < 9; ++kk) xd_l[t*36 + w + 4*kk] = p[kk];
            }
        }
        if (t_last < t0 + TT) {
            int tl = t_last - t0;
            float pc[4];
            #pragma unroll
            for (int k = 0; k < 4; ++k) pc[k] = 0.f;
            #pragma unroll
            for (int i = 0; i < 10; ++i) {
                float ui = u_l[tl*641 + l + 64*i];
                #pragma unroll
                for (int k = 0; k < 4; ++k)
                    pc[k] = fmaf(xW[(size_t)(36 + w + 4*k)*D_INNER + l + 64*i], ui, pc[k]);
            }
            #pragma unroll
            for (int o = 32; o; o >>= 1) {
                #pragma unroll
                for (int k = 0; k < 4; ++k) pc[k] += __shfl_xor(pc[k], o);
            }
            if (l == 0) {
                #pragma unroll
                for (int k = 0; k < 4; ++k) ws[OFF_CLAST + b*16 + w + 4*k] = pc[k];
            }
        }
    }
    __syncthreads();

    {
        int tmax = min(TT-1, t_last - t0);
        int cnt = (tmax + 1) * 36;
        float* dst = ws + OFF_XD + ((size_t)b*L_ + t0)*36;
        for (int o = tid; o < cnt; o += 256) dst[o] = xd_l[o];
    }
}

// ---------- K3: chunk-parallel fused scan ----------
// Production: (dd = tid&15 -> one d, tg = tid>>4 -> 4 t). Also transposes B -> Bb[s][t]
// and accumulates per-d sum-of-delta (sd hoisted out of recurrence).
// Recurrence: (dl = tid>>4 -> d, s = tid&15). All-b128 LDS reads.
__global__ __launch_bounds__(256) void k_scanc(
    const int* __restrict__ idx, const int* __restrict__ tissue_id,
    const int* __restrict__ seq_lengths,
    const float* __restrict__ conv_w, const float* __restrict__ conv_b,
    const float* __restrict__ dtW, const float* __restrict__ dtb,
    const float* __restrict__ A_log, float* __restrict__ ws)
{
    __shared__ float xd_t[ST*36];          // [t][36]
    __shared__ float dl_t[16*72];          // [d][t] stride 72 (b128-aligned)
    __shared__ float du_t[16*72];
    __shared__ float Bb_t[16*72];          // [s][t] transposed B
    __shared__ float sdred[16*17];         // [tg][dd] per-d delta partial sums
    __shared__ int   idx_t[ST+3];

    int b = blockIdx.y, dg = blockIdx.x, c = blockIdx.z;
    int t_last = seq_lengths[b] - 1;
    int t_begin = c * CHLEN;
    if (t_begin > t_last) return;
    int t_end = min(t_begin + CHLEN - 1, t_last);
    int tid = threadIdx.x;
    int dl = tid >> 4, s = tid & 15;
    int dd = tid & 15, tg = tid >> 4;
    int d_own = dg*16 + dd;
    int tis = tissue_id[b];
    const float* Mseq = ws + OFF_MSEQ;

    float dtw_r[20];
    #pragma unroll
    for (int i = 0; i < 20; i += 4) {
        float4 w4 = *(const float4*)(dtW + d_own*20 + i);
        dtw_r[i] = w4.x; dtw_r[i+1] = w4.y; dtw_r[i+2] = w4.z; dtw_r[i+3] = w4.w;
    }
    float4 cw4 = *(const float4*)(conv_w + d_own*4);
    float  cb  = conv_b[d_own];
    float  dtb_v = dtb[d_own];
    float  mt  = ws[OFF_MTIS + (size_t)tis*1280 + d_own];
    float As = -__expf(A_log[(dg*16 + dl)*D_STATE + s]) * 1.44269504089f;

    float h = 0.0f;
    float sdp = 0.0f;   // production-side partial sum of delta for (d_own, this thread's t's)
    for (int t0 = t_begin; t0 <= t_end; t0 += ST) {
        int nt = min(ST, t_end - t0 + 1);
        if (tid < ST+3) {
            int t = t0 - 3 + tid;
            idx_t[tid] = (t >= 0 && t < L_) ? idx[b*L_ + t] : 0;
        }
        {
            const float4* src = (const float4*)(ws + OFF_XD + ((size_t)b*L_ + t0)*36);
            float4* dst = (float4*)xd_t;
            int cnt4 = nt * 9;
            for (int o = tid; o < cnt4; o += 256) dst[o] = src[o];
        }
        __syncthreads();

        // production: (d_own, t = tg*4..tg*4+3) + B-transpose (s=dd, same t range)
        {
            int ttb = tg * 4;
            if (ttb < nt) {
                float xz[7];
                #pragma unroll
                for (int k = 0; k < 7; ++k) {
                    int row = idx_t[ttb + k];
                    xz[k] = row ? (Mseq[(size_t)row*1280 + d_own] + mt) : 0.0f;
                }
                float dl4[4], du4[4], bb4[4];
                bool full = (ttb + 3 < nt);
                #pragma unroll
                for (int j = 0; j < 4; ++j) {
                    int tt = ttb + j;
                    if (full || tt < nt) {
                        float cc = cb;
                        cc = fmaf(cw4.x, xz[j+0], cc);
                        cc = fmaf(cw4.y, xz[j+1], cc);
                        cc = fmaf(cw4.z, xz[j+2], cc);
                        cc = fmaf(cw4.w, xz[j+3], cc);
                        float u = silu_f(cc);
                        const float* xr = xd_t + tt*36;
                        float x = dtb_v;
                        #pragma unroll
                        for (int r = 0; r < 20; r += 4) {
                            float4 x4 = *(const float4*)(xr + r);
                            x = fmaf(x4.x, dtw_r[r+0], x);
                            x = fmaf(x4.y, dtw_r[r+1], x);
                            x = fmaf(x4.z, dtw_r[r+2], x);
                            x = fmaf(x4.w, dtw_r[r+3], x);
                        }
                        float e = __expf(-fabsf(x));
                        float sp = fmaxf(x, 0.0f) + __logf(1.0f + e);
                        dl4[j] = sp;
                        du4[j] = sp * u;
                        sdp += sp;
                        bb4[j] = xd_t[tt*36 + 20 + dd];   // B[s=dd][t=tt]
                    } else { dl4[j] = 0.f; du4[j] = 0.f; bb4[j] = 0.f; }
                }
                if (full) {
                    *(float4*)(dl_t + dd*72 + ttb) = make_float4(dl4[0], dl4[1], dl4[2], dl4[3]);
                    *(float4*)(du_t + dd*72 + ttb) = make_float4(du4[0], du4[1], du4[2], du4[3]);
                    *(float4*)(Bb_t + dd*72 + ttb) = make_float4(bb4[0], bb4[1], bb4[2], bb4[3]);
                } else {
                    for (int j = 0; j < 4 && ttb + j < nt; ++j) {
                        dl_t[dd*72 + ttb + j] = dl4[j];
                        du_t[dd*72 + ttb + j] = du4[j];
                        Bb_t[dd*72 + ttb + j] = bb4[j];
                    }
                }
            }
        }
        __syncthreads();

        // recurrence: (dl, s) — pure b128 reads, no sd accumulation
        {
            int q4 = nt >> 2;
            #pragma unroll 8
            for (int q = 0; q < q4; ++q) {
                float4 d4 = *(const float4*)(dl_t + dl*72 + 4*q);
                float4 u4 = *(const float4*)(du_t + dl*72 + 4*q);
                float4 b4 = *(const float4*)(Bb_t + s*72 + 4*q);
                h = fmaf(exp2f(d4.x*As), h, u4.x*b4.x);
                h = fmaf(exp2f(d4.y*As), h, u4.y*b4.y);
                h = fmaf(exp2f(d4.z*As), h, u4.z*b4.z);
                h = fmaf(exp2f(d4.w*As), h, u4.w*b4.w);
            }
            for (int tt = q4*4; tt < nt; ++tt) {
                float dlt = dl_t[dl*72 + tt];
                h = fmaf(exp2f(dlt * As), h, du_t[dl*72 + tt] * Bb_t[s*72 + tt]);
            }
        }
        __syncthreads();
    }
    // reduce per-d delta sums: sdred[tg][dd] = sdp, then thread (dl,s) sums over tg for d=dl
    sdred[tg*17 + dd] = sdp;
    __syncthreads();
    float sd = 0.0f;
    #pragma unroll
    for (int g = 0; g < 16; ++g) sd += sdred[g*17 + dl];
    float P = exp2f(As * sd);
    size_t base = (((size_t)b*NCHUNK + c)*40 + dg)*256 + tid;
    ws[OFF_PC + base] = P;
    ws[OFF_SC + base] = h;
}

// ---------- K3b: combine chunk transfers, apply C_last, reduce over s (coalesced, 640 blocks) ----------
__global__ __launch_bounds__(256) void k_comb(const int* __restrict__ seq_lengths,
                                              float* __restrict__ ws)
{
    int b = blockIdx.y, dg = blockIdx.x;
    int tid = threadIdx.x;
    int dl = tid >> 4, s = tid & 15;
    int t_last = seq_lengths[b] - 1;
    int ncv = t_last / CHLEN + 1;
    float h = 0.0f;
    for (int c = 0; c < ncv; ++c) {
        size_t base = (((size_t)b*NCHUNK + c)*40 + dg)*256 + tid;
        h = fmaf(ws[OFF_PC + base], h, ws[OFF_SC + base]);
    }
    float v = h * ws[OFF_CLAST + b*16 + s];
    v += __shfl_xor(v, 1); v += __shfl_xor(v, 2);
    v += __shfl_xor(v, 4); v += __shfl_xor(v, 8);
    if (s == 0) ws[OFF_YSCAN + (size_t)b*D_INNER + dg*16 + dl] = v;
}

// ---------- K5: per-batch epilogue: skip + gate + out_proj + MLP head ----------
__global__ __launch_bounds__(320) void k_final(
    const int* __restrict__ idx, const int* __restrict__ tissue_id,
    const int* __restrict__ seq_lengths,
    const float* __restrict__ conv_w, const float* __restrict__ conv_b,
    const float* __restrict__ Dskip, const float* __restrict__ outW,
    const float* __restrict__ p1W, const float* __restrict__ p1b,
    const float* __restrict__ p2W, const float* __restrict__ p2b,
    const float* __restrict__ ws, float* __restrict__ out)
{
    __shared__ float y_l[D_INNER];
    __shared__ float o_l[D_MODEL];
    __shared__ float h1_l[H_OUT];
    int b = blockIdx.x, tid = threadIdx.x;
    int t_last = seq_lengths[b] - 1;
    int tis = tissue_id[b];
    const float* Mseq = ws + OFF_MSEQ;
    const float* Mtis = ws + OFF_MTIS;
    int rows[4];
    #pragma unroll
    for (int k = 0; k < 4; ++k) {
        int t = t_last - 3 + k;
        rows[k] = (t >= 0) ? idx[b*L_ + t] : 0;
    }
    for (int d = tid; d < D_INNER; d += 320) {
        float conv = conv_b[d];
        const float* cw = conv_w + d*4;
        #pragma unroll
        for (int k = 0; k < 4; ++k) {
            int row = rows[k];
            float xzv = row ? (Mseq[(size_t)row*1280 + d] + Mtis[(size_t)tis*1280 + d]) : 0.0f;
            conv += cw[k] * xzv;
        }
        float u = silu_f(conv);
        int rowL = rows[3];
        float z = rowL ? (Mseq[(size_t)rowL*1280 + 640 + d] + Mtis[(size_t)tis*1280 + 640 + d]) : 0.0f;
        float ys = ws[OFF_YSCAN + (size_t)b*D_INNER + d];
        y_l[d] = (ys + u * Dskip[d]) * silu_f(z);
    }
    __syncthreads();
    if (tid < D_MODEL) {
        const float* w = outW + tid*D_INNER;
        float acc = 0.f;
        #pragma unroll 4
        for (int k = 0; k < D_INNER; k += 4) {
            float4 w4 = *(const float4*)(w + k);
            acc += y_l[k]*w4.x + y_l[k+1]*w4.y + y_l[k+2]*w4.z + y_l[k+3]*w4.w;
        }
        o_l[tid] = acc;
    }
    __syncthreads();
    if (tid < H_OUT) {
        const float* w = p1W + tid*D_MODEL;
        float acc = p1b[tid];
        #pragma unroll 4
        for (int k = 0; k < D_MODEL; k += 4) {
            float4 w4 = *(const float4*)(w + k);
            acc += o_l[k]*w4.x + o_l[k+1]*w4.y + o_l[k+2]*w4.z + o_l[k+3]*w4.w;
        }
        h1_l[tid] = fmaxf(acc, 0.0f);
    }
    __syncthreads();
    if (tid == 0) {
        float acc = p2b[0];
        for (int k = 0; k < H_OUT; ++k) acc += h1_l[k]*p2W[k];
        out[b] = acc;
    }
}

extern "C" void kernel_launch(void* const* d_in, const int* in_sizes, int n_in,
                              void* d_out, int out_size, void* d_ws, size_t ws_size,
                              hipStream_t stream)
{
    const int*   idx   = (const int*)d_in[0];
    const int*   tis   = (const int*)d_in[1];
    const int*   slen  = (const int*)d_in[2];
    const float* seqW  = (const float*)d_in[3];
    const float* tisW  = (const float*)d_in[4];
    const float* inW   = (const float*)d_in[5];
    const float* convw = (const float*)d_in[6];
    const float* convb = (const float*)d_in[7];
    const float* xW    = (const float*)d_in[8];
    const float* dtW   = (const float*)d_in[9];
    const float* dtb   = (const float*)d_in[10];
    const float* Alog  = (const float*)d_in[11];
    const float* Dsk   = (const float*)d_in[12];
    const float* outW  = (const float*)d_in[13];
    const float* p1W   = (const float*)d_in[14];
    const float* p1b   = (const float*)d_in[15];
    const float* p2W   = (const float*)d_in[16];
    const float* p2b   = (const float*)d_in[17];
    float* ws  = (float*)d_ws;
    float* out = (float*)d_out;

    hipLaunchKernelGGL(k_mbuild, dim3(VOCAB + N_TIS, 5), dim3(256), 0, stream, seqW, tisW, inW, ws);
    hipLaunchKernelGGL(k_xdbl,   dim3(L_/TT, B_),        dim3(256), 0, stream,
                       idx, tis, slen, convw, convb, xW, ws);
    hipLaunchKernelGGL(k_scanc,  dim3(D_INNER/16, B_, NCHUNK), dim3(256), 0, stream,
                       idx, tis, slen, convw, convb, dtW, dtb, Alog, ws);
    hipLaunchKernelGGL(k_comb,   dim3(D_INNER/16, B_),   dim3(256), 0, stream, slen, ws);
    hipLaunchKernelGGL(k_final,  dim3(B_),               dim3(320), 0, stream,
                       idx, tis, slen, convw, convb, Dsk, outW, p1W, p1b, p2W, p2b, ws, out);
}

// Round 11
// 269.878 us; speedup vs baseline: 1.9056x; 1.0001x over previous
//
#include <hip/hip_runtime.h>
#include <hip/hip_bf16.h>
#include <math.h>

#define B_      16
#define L_      2048
#define D_MODEL 320
#define D_INNER 640
#define D_STATE 16
#define DT_RANK 20
#define H_OUT   128
#define VOCAB   65
#define N_TIS   30
#define TT      8    // t-tile in xdbl producer
#define ST      64   // t-tile in fused scan
#define NCHUNK  16   // scan chunks (128 t each)
#define CHLEN   (L_/NCHUNK)

// workspace layout (floats)
static constexpr size_t OFF_MSEQ  = 0;                          // 65*1280
static constexpr size_t OFF_MTIS  = OFF_MSEQ + VOCAB*1280;      // 30*1280
static constexpr size_t OFF_YSCAN = OFF_MTIS + N_TIS*1280;      // 16*640
static constexpr size_t OFF_CLAST = OFF_YSCAN + B_*D_INNER;     // 16*16
static constexpr size_t OFF_XD20  = OFF_CLAST + B_*16;          // B*L*20 (dt rows only)
static constexpr size_t OFF_BBAR  = OFF_XD20 + (size_t)B_*L_*20;// B*16*L (B transposed [b][s][t])
static constexpr size_t OFF_PC    = OFF_BBAR + (size_t)B_*D_STATE*L_;
static constexpr size_t OFF_SC    = OFF_PC + (size_t)B_*NCHUNK*40*256;

__device__ __forceinline__ float silu_f(float x) { return x / (1.0f + __expf(-x)); }

// ---------- A0+A1 fused: renorm embedding row (max_norm=2) then M-row = row @ inW-slice^T ----------
__global__ __launch_bounds__(256) void k_mbuild(
    const float* __restrict__ seqW, const float* __restrict__ tisW,
    const float* __restrict__ inW, float* __restrict__ ws)
{
    __shared__ float a_l[256];
    __shared__ float red[4];
    int v = blockIdx.x, tid = threadIdx.x;
    int K, wofs; const float* src; float* dstM;
    if (v < VOCAB) { K = 256; wofs = 0;   src = seqW + (size_t)v*256;        dstM = ws + OFF_MSEQ + (size_t)v*1280; }
    else           { K = 64;  wofs = 256; src = tisW + (size_t)(v-VOCAB)*64; dstM = ws + OFF_MTIS + (size_t)(v-VOCAB)*1280; }
    float x = (tid < K) ? src[tid] : 0.0f;
    float ss = x * x;
    #pragma unroll
    for (int o = 32; o; o >>= 1) ss += __shfl_xor(ss, o);
    if ((tid & 63) == 0) red[tid >> 6] = ss;
    __syncthreads();
    float tot = red[0] + red[1] + red[2] + red[3];
    float scale = fminf(1.0f, 2.0f / fmaxf(sqrtf(tot), 1e-12f));
    if (tid < K) a_l[tid] = x * scale;
    __syncthreads();

    int j = blockIdx.y * 256 + tid;
    const float* w = inW + (size_t)j*320 + wofs;
    float ac0 = 0.f, ac1 = 0.f, ac2 = 0.f, ac3 = 0.f;
    #pragma unroll 4
    for (int k = 0; k < K; k += 4) {
        float4 w4 = *(const float4*)(w + k);
        ac0 += a_l[k+0]*w4.x; ac1 += a_l[k+1]*w4.y;
        ac2 += a_l[k+2]*w4.z; ac3 += a_l[k+3]*w4.w;
    }
    dstM[j] = (ac0 + ac1) + (ac2 + ac3);
}

// ---------- K2: conv+silu -> x_proj rows 0..35 -> XD20 [b][t][20] + BBAR [b][s][t]; C at t_last ----------
__global__ __launch_bounds__(256) void k_xdbl(
    const int* __restrict__ idx, const int* __restrict__ tissue_id,
    const int* __restrict__ seq_lengths,
    const float* __restrict__ conv_w, const float* __restrict__ conv_b,
    const float* __restrict__ xW, float* __restrict__ ws)
{
    __shared__ float u_l[TT*641];
    __shared__ float xd_l[TT*36];
    __shared__ int   idx_l[TT+3];
    int b = blockIdx.y;
    int t0 = blockIdx.x * TT;
    int t_last = seq_lengths[b] - 1;
    if (t0 > t_last) return;
    int tid = threadIdx.x;
    const float* Mseq = ws + OFF_MSEQ;
    const float* Mtis = ws + OFF_MTIS;
    int tis = tissue_id[b];
    if (tid < TT+3) {
        int t = t0 - 3 + tid;
        idx_l[tid] = (t >= 0) ? idx[b*L_ + t] : 0;
    }
    __syncthreads();

    for (int d = tid; d < D_INNER; d += 256) {
        float w0 = conv_w[d*4+0], w1 = conv_w[d*4+1], w2 = conv_w[d*4+2], w3 = conv_w[d*4+3];
        float cb = conv_b[d];
        float mt = Mtis[(size_t)tis*1280 + d];
        float xzv[TT+3];
        #pragma unroll
        for (int k = 0; k < TT+3; ++k) {
            int row = idx_l[k];
            xzv[k] = row ? (Mseq[(size_t)row*1280 + d] + mt) : 0.0f;
        }
        #pragma unroll
        for (int t = 0; t < TT; ++t) {
            float c = cb;
            c = fmaf(w0, xzv[t+0], c);
            c = fmaf(w1, xzv[t+1], c);
            c = fmaf(w2, xzv[t+2], c);
            c = fmaf(w3, xzv[t+3], c);
            u_l[t*641 + d] = silu_f(c);
        }
    }
    __syncthreads();

    {
        int w = tid >> 6, l = tid & 63;
        float wreg[9][10];
        #pragma unroll
        for (int kk = 0; kk < 9; ++kk) {
            const float* xr = xW + (size_t)(w + 4*kk)*D_INNER + l;
            #pragma unroll
            for (int i = 0; i < 10; ++i) wreg[kk][i] = xr[64*i];
        }
        for (int t = 0; t < TT; ++t) {
            float p[9];
            #pragma unroll
            for (int kk = 0; kk < 9; ++kk) p[kk] = 0.f;
            #pragma unroll
            for (int i = 0; i < 10; ++i) {
                float ui = u_l[t*641 + l + 64*i];
                #pragma unroll
                for (int kk = 0; kk < 9; ++kk) p[kk] = fmaf(wreg[kk][i], ui, p[kk]);
            }
            #pragma unroll
            for (int o = 32; o; o >>= 1) {
                #pragma unroll
                for (int kk = 0; kk < 9; ++kk) p[kk] += __shfl_xor(p[kk], o);
            }
            if (l == t) {
                #pragma unroll
                for (int kk = 0; kk < 9; ++kk) xd_l[t*36 + w + 4*kk] = p[kk];
            }
        }
        if (t_last < t0 + TT) {
            int tl = t_last - t0;
            float pc[4];
            #pragma unroll
            for (int k = 0; k < 4; ++k) pc[k] = 0.f;
            #pragma unroll
            for (int i = 0; i < 10; ++i) {
                float ui = u_l[tl*641 + l + 64*i];
                #pragma unroll
                for (int k = 0; k < 4; ++k)
                    pc[k] = fmaf(xW[(size_t)(36 + w + 4*k)*D_INNER + l + 64*i], ui, pc[k]);
            }
            #pragma unroll
            for (int o = 32; o; o >>= 1) {
                #pragma unroll
                for (int k = 0; k < 4; ++k) pc[k] += __shfl_xor(pc[k], o);
            }
            if (l == 0) {
                #pragma unroll
                for (int k = 0; k < 4; ++k) ws[OFF_CLAST + b*16 + w + 4*k] = pc[k];
            }
        }
    }
    __syncthreads();

    // write-out: dt rows -> XD20 (coalesced); B rows -> BBAR [b][s][t] (t-runs per s)
    {
        int nt = min(TT, t_last - t0 + 1);
        int cnt = nt * 20;
        float* dst = ws + OFF_XD20 + ((size_t)b*L_ + t0)*20;
        for (int o = tid; o < cnt; o += 256) {
            int t = o / 20, r = o - t*20;
            dst[o] = xd_l[t*36 + r];
        }
        int cntB = nt * 16;
        if (tid < cntB) {
            int s, tt;
            if (nt == TT) { s = tid >> 3; tt = tid & 7; }
            else          { s = tid / nt; tt = tid - s*nt; }
            ws[OFF_BBAR + ((size_t)b*D_STATE + s)*L_ + t0 + tt] = xd_l[tt*36 + 20 + s];
        }
    }
}

// ---------- K3: chunk-parallel fused scan ----------
// Production: (dd = tid&15 -> one d, tg = tid>>4 -> 4 t); sd hoisted.
// Recurrence: (dl = tid>>4 -> d, s = tid&15). Strides 68 (== 4 mod 32 -> 2-way max, free).
__global__ __launch_bounds__(256) void k_scanc(
    const int* __restrict__ idx, const int* __restrict__ tissue_id,
    const int* __restrict__ seq_lengths,
    const float* __restrict__ conv_w, const float* __restrict__ conv_b,
    const float* __restrict__ dtW, const float* __restrict__ dtb,
    const float* __restrict__ A_log, float* __restrict__ ws)
{
    __shared__ float xd_t[ST*20];          // [t][20] dt rows only
    __shared__ float dl_t[16*68];          // [d][t] stride 68
    __shared__ float du_t[16*68];
    __shared__ float Bb_t[16*68];          // [s][t] staged from BBAR
    __shared__ float sdred[16*17];         // [tg][dd]
    __shared__ int   idx_t[ST+3];

    int b = blockIdx.y, dg = blockIdx.x, c = blockIdx.z;
    int t_last = seq_lengths[b] - 1;
    int t_begin = c * CHLEN;
    if (t_begin > t_last) return;
    int t_end = min(t_begin + CHLEN - 1, t_last);
    int tid = threadIdx.x;
    int dl = tid >> 4, s = tid & 15;
    int dd = tid & 15, tg = tid >> 4;
    int d_own = dg*16 + dd;
    int tis = tissue_id[b];
    const float* Mseq = ws + OFF_MSEQ;

    float dtw_r[20];
    #pragma unroll
    for (int i = 0; i < 20; i += 4) {
        float4 w4 = *(const float4*)(dtW + d_own*20 + i);
        dtw_r[i] = w4.x; dtw_r[i+1] = w4.y; dtw_r[i+2] = w4.z; dtw_r[i+3] = w4.w;
    }
    float4 cw4 = *(const float4*)(conv_w + d_own*4);
    float  cb  = conv_b[d_own];
    float  dtb_v = dtb[d_own];
    float  mt  = ws[OFF_MTIS + (size_t)tis*1280 + d_own];
    float As = -__expf(A_log[(dg*16 + dl)*D_STATE + s]) * 1.44269504089f;

    float h = 0.0f;
    float sdp = 0.0f;
    for (int t0 = t_begin; t0 <= t_end; t0 += ST) {
        int nt = min(ST, t_end - t0 + 1);
        if (tid < ST+3) {
            int t = t0 - 3 + tid;
            idx_t[tid] = (t >= 0 && t < L_) ? idx[b*L_ + t] : 0;
        }
        {   // stage xd20 tile (5 float4 per t)
            const float4* src = (const float4*)(ws + OFF_XD20 + ((size_t)b*L_ + t0)*20);
            float4* dst = (float4*)xd_t;
            int cnt4 = nt * 5;
            for (int o = tid; o < cnt4; o += 256) dst[o] = src[o];
        }
        {   // stage Bb tile: one coalesced float4 per thread
            int lr = tid >> 4, c4 = (tid & 15) * 4;
            if (c4 < nt)
                *(float4*)(Bb_t + lr*68 + c4) =
                    *(const float4*)(ws + OFF_BBAR + ((size_t)b*D_STATE + lr)*L_ + t0 + c4);
        }
        __syncthreads();

        // production: (d_own, t = tg*4..tg*4+3)
        {
            int ttb = tg * 4;
            if (ttb < nt) {
                float xz[7];
                #pragma unroll
                for (int k = 0; k < 7; ++k) {
                    int row = idx_t[ttb + k];
                    xz[k] = row ? (Mseq[(size_t)row*1280 + d_own] + mt) : 0.0f;
                }
                float dl4[4], du4[4];
                bool full = (ttb + 3 < nt);
                #pragma unroll
                for (int j = 0; j < 4; ++j) {
                    int tt = ttb + j;
                    if (full || tt < nt) {
                        float cc = cb;
                        cc = fmaf(cw4.x, xz[j+0], cc);
                        cc = fmaf(cw4.y, xz[j+1], cc);
                        cc = fmaf(cw4.z, xz[j+2], cc);
                        cc = fmaf(cw4.w, xz[j+3], cc);
                        float u = silu_f(cc);
                        const float* xr = xd_t + tt*20;
                        float x = dtb_v;
                        #pragma unroll
                        for (int r = 0; r < 20; r += 4) {
                            float4 x4 = *(const float4*)(xr + r);
                            x = fmaf(x4.x, dtw_r[r+0], x);
                            x = fmaf(x4.y, dtw_r[r+1], x);
                            x = fmaf(x4.z, dtw_r[r+2], x);
                            x = fmaf(x4.w, dtw_r[r+3], x);
                        }
                        float e = __expf(-fabsf(x));
                        float sp = fmaxf(x, 0.0f) + __logf(1.0f + e);
                        dl4[j] = sp;
                        du4[j] = sp * u;
                        sdp += sp;
                    } else { dl4[j] = 0.f; du4[j] = 0.f; }
                }
                if (full) {
                    *(float4*)(dl_t + dd*68 + ttb) = make_float4(dl4[0], dl4[1], dl4[2], dl4[3]);
                    *(float4*)(du_t + dd*68 + ttb) = make_float4(du4[0], du4[1], du4[2], du4[3]);
                } else {
                    for (int j = 0; j < 4 && ttb + j < nt; ++j) {
                        dl_t[dd*68 + ttb + j] = dl4[j];
                        du_t[dd*68 + ttb + j] = du4[j];
                    }
                }
            }
        }
        __syncthreads();

        // recurrence: (dl, s) — b128 reads at conflict-free strides
        {
            int q4 = nt >> 2;
            #pragma unroll 8
            for (int q = 0; q < q4; ++q) {
                float4 d4 = *(const float4*)(dl_t + dl*68 + 4*q);
                float4 u4 = *(const float4*)(du_t + dl*68 + 4*q);
                float4 b4 = *(const float4*)(Bb_t + s*68 + 4*q);
                h = fmaf(exp2f(d4.x*As), h, u4.x*b4.x);
                h = fmaf(exp2f(d4.y*As), h, u4.y*b4.y);
                h = fmaf(exp2f(d4.z*As), h, u4.z*b4.z);
                h = fmaf(exp2f(d4.w*As), h, u4.w*b4.w);
            }
            for (int tt = q4*4; tt < nt; ++tt) {
                float dlt = dl_t[dl*68 + tt];
                h = fmaf(exp2f(dlt * As), h, du_t[dl*68 + tt] * Bb_t[s*68 + tt]);
            }
        }
        __syncthreads();
    }
    sdred[tg*17 + dd] = sdp;
    __syncthreads();
    float sd = 0.0f;
    #pragma unroll
    for (int g = 0; g < 16; ++g) sd += sdred[g*17 + dl];
    float P = exp2f(As * sd);
    size_t base = (((size_t)b*NCHUNK + c)*40 + dg)*256 + tid;
    ws[OFF_PC + base] = P;
    ws[OFF_SC + base] = h;
}

// ---------- K3b: combine chunk transfers, apply C_last, reduce over s ----------
__global__ __launch_bounds__(256) void k_comb(const int* __restrict__ seq_lengths,
                                              float* __restrict__ ws)
{
    int b = blockIdx.y, dg = blockIdx.x;
    int tid = threadIdx.x;
    int dl = tid >> 4, s = tid & 15;
    int t_last = seq_lengths[b] - 1;
    int ncv = t_last / CHLEN + 1;
    float h = 0.0f;
    for (int c = 0; c < ncv; ++c) {
        size_t base = (((size_t)b*NCHUNK + c)*40 + dg)*256 + tid;
        h = fmaf(ws[OFF_PC + base], h, ws[OFF_SC + base]);
    }
    float v = h * ws[OFF_CLAST + b*16 + s];
    v += __shfl_xor(v, 1); v += __shfl_xor(v, 2);
    v += __shfl_xor(v, 4); v += __shfl_xor(v, 8);
    if (s == 0) ws[OFF_YSCAN + (size_t)b*D_INNER + dg*16 + dl] = v;
}

// ---------- K5: per-batch epilogue: skip + gate + out_proj + MLP head ----------
__global__ __launch_bounds__(320) void k_final(
    const int* __restrict__ idx, const int* __restrict__ tissue_id,
    const int* __restrict__ seq_lengths,
    const float* __restrict__ conv_w, const float* __restrict__ conv_b,
    const float* __restrict__ Dskip, const float* __restrict__ outW,
    const float* __restrict__ p1W, const float* __restrict__ p1b,
    const float* __restrict__ p2W, const float* __restrict__ p2b,
    const float* __restrict__ ws, float* __restrict__ out)
{
    __shared__ float y_l[D_INNER];
    __shared__ float o_l[D_MODEL];
    __shared__ float h1_l[H_OUT];
    int b = blockIdx.x, tid = threadIdx.x;
    int t_last = seq_lengths[b] - 1;
    int tis = tissue_id[b];
    const float* Mseq = ws + OFF_MSEQ;
    const float* Mtis = ws + OFF_MTIS;
    int rows[4];
    #pragma unroll
    for (int k = 0; k < 4; ++k) {
        int t = t_last - 3 + k;
        rows[k] = (t >= 0) ? idx[b*L_ + t] : 0;
    }
    for (int d = tid; d < D_INNER; d += 320) {
        float conv = conv_b[d];
        const float* cw = conv_w + d*4;
        #pragma unroll
        for (int k = 0; k < 4; ++k) {
            int row = rows[k];
            float xzv = row ? (Mseq[(size_t)row*1280 + d] + Mtis[(size_t)tis*1280 + d]) : 0.0f;
            conv += cw[k] * xzv;
        }
        float u = silu_f(conv);
        int rowL = rows[3];
        float z = rowL ? (Mseq[(size_t)rowL*1280 + 640 + d] + Mtis[(size_t)tis*1280 + 640 + d]) : 0.0f;
        float ys = ws[OFF_YSCAN + (size_t)b*D_INNER + d];
        y_l[d] = (ys + u * Dskip[d]) * silu_f(z);
    }
    __syncthreads();
    if (tid < D_MODEL) {
        const float* w = outW + tid*D_INNER;
        float acc = 0.f;
        #pragma unroll 4
        for (int k = 0; k < D_INNER; k += 4) {
            float4 w4 = *(const float4*)(w + k);
            acc += y_l[k]*w4.x + y_l[k+1]*w4.y + y_l[k+2]*w4.z + y_l[k+3]*w4.w;
        }
        o_l[tid] = acc;
    }
    __syncthreads();
    if (tid < H_OUT) {
        const float* w = p1W + tid*D_MODEL;
        float acc = p1b[tid];
        #pragma unroll 4
        for (int k = 0; k < D_MODEL; k += 4) {
            float4 w4 = *(const float4*)(w + k);
            acc += o_l[k]*w4.x + o_l[k+1]*w4.y + o_l[k+2]*w4.z + o_l[k+3]*w4.w;
        }
        h1_l[tid] = fmaxf(acc, 0.0f);
    }
    __syncthreads();
    if (tid == 0) {
        float acc = p2b[0];
        for (int k = 0; k < H_OUT; ++k) acc += h1_l[k]*p2W[k];
        out[b] = acc;
    }
}

extern "C" void kernel_launch(void* const* d_in, const int* in_sizes, int n_in,
                              void* d_out, int out_size, void* d_ws, size_t ws_size,
                              hipStream_t stream)
{
    const int*   idx   = (const int*)d_in[0];
    const int*   tis   = (const int*)d_in[1];
    const int*   slen  = (const int*)d_in[2];
    const float* seqW  = (const float*)d_in[3];
    const float* tisW  = (const float*)d_in[4];
    const float* inW   = (const float*)d_in[5];
    const float* convw = (const float*)d_in[6];
    const float* convb = (const float*)d_in[7];
    const float* xW    = (const float*)d_in[8];
    const float* dtW   = (const float*)d_in[9];
    const float* dtb   = (const float*)d_in[10];
    const float* Alog  = (const float*)d_in[11];
    const float* Dsk   = (const float*)d_in[12];
    const float* outW  = (const float*)d_in[13];
    const float* p1W   = (const float*)d_in[14];
    const float* p1b   = (const float*)d_in[15];
    const float* p2W   = (const float*)d_in[16];
    const float* p2b   = (const float*)d_in[17];
    float* ws  = (float*)d_ws;
    float* out = (float*)d_out;

    hipLaunchKernelGGL(k_mbuild, dim3(VOCAB + N_TIS, 5), dim3(256), 0, stream, seqW, tisW, inW, ws);
    hipLaunchKernelGGL(k_xdbl,   dim3(L_/TT, B_),        dim3(256), 0, stream,
                       idx, tis, slen, convw, convb, xW, ws);
    hipLaunchKernelGGL(k_scanc,  dim3(D_INNER/16, B_, NCHUNK), dim3(256), 0, stream,
                       idx, tis, slen, convw, convb, dtW, dtb, Alog, ws);
    hipLaunchKernelGGL(k_comb,   dim3(D_INNER/16, B_),   dim3(256), 0, stream, slen, ws);
    hipLaunchKernelGGL(k_final,  dim3(B_),               dim3(320), 0, stream,
                       idx, tis, slen, convw, convb, Dsk, outW, p1W, p1b, p2W, p2b, ws, out);
}